// Round 2
// baseline (542.285 us; speedup 1.0000x reference)
//
#include <hip/hip_runtime.h>
#include <math.h>

#define DPI 3.141592653589793238462643383279502884

// ---------------- device helpers ----------------
__device__ __forceinline__ float wave_sum64(float v) {
#pragma unroll
  for (int off = 32; off > 0; off >>= 1) v += __shfl_xor(v, off, 64);
  return v;
}

__device__ __forceinline__ float gelu_tanh(float v) {
  float u = 0.7978845608028654f * (v + 0.044715f * v * v * v);
  return 0.5f * v * (1.0f + tanhf(u));
}

// ---------------- constant builders ----------------
// MW quadrature weights for L=128 (255 extended thetas)
__global__ void ct_wq(double* wq) {
  int t = blockIdx.x * blockDim.x + threadIdx.x;
  if (t >= 255) return;
  double th = (2.0 * t + 1.0) * DPI / 255.0;
  double s = 2.0 - DPI * sin(th);           // k=0 term + k=+-1 terms
  for (int k = 2; k <= 126; k += 2)
    s += 4.0 * cos(k * th) / (1.0 - (double)k * (double)k);
  wq[t] = s / 255.0;
}

// twiddle tables: tw255 = (cos, -sin)(2*pi*k/255) for forward DFT;
//                 tw127 = (cos, +sin)(2*pi*k/127) for inverse DFT
__global__ void ct_tw(float* tw255, float* tw127) {
  int k = threadIdx.x;
  if (k < 255) {
    double a = 2.0 * DPI * k / 255.0;
    tw255[2 * k] = (float)cos(a);
    tw255[2 * k + 1] = (float)(-sin(a));
  }
  if (k < 127) {
    double a = 2.0 * DPI * k / 127.0;
    tw127[2 * k] = (float)cos(a);
    tw127[2 * k + 1] = (float)sin(a);
  }
}

// Wigner d^l_{m,-1}(theta) via Varshalovich 3-term recurrence in l.
// mode 0: Deff for forward (t=0..127, theta=(2t+1)pi/255), folded with
//         quad weights (+ theta-extension fold), CL_IN[l], and 2*pi/255.
// mode 1: Dinv for inverse (t=0..63, theta=(2t+1)pi/127), folded with CL_OUT[l].
// Layout: out[(t*64+l)*127+mm], mm = m+63, zero where l < max(|m|,1).
// NOTE: m range is [-l, +l] INCLUSIVE (the reference slice L-1-l:L+l is 2l+1 wide).
__global__ void ct_wigner(float* out, const double* wq, int mode) {
  int nth = (mode == 0) ? 128 : 64;
  int tid = blockIdx.x * blockDim.x + threadIdx.x;
  if (tid >= nth * 127) return;
  int t = tid / 127, mm = tid % 127;
  int m = mm - 63;
  double denomN = (mode == 0) ? 255.0 : 127.0;
  double beta = (2.0 * t + 1.0) * DPI / denomN;
  double cb = cos(beta);
  double ch = cos(0.5 * beta), sh = sin(0.5 * beta);
  double coef = 1.0;
  if (mode == 0) {
    double w = (t < 127) ? (wq[t] + wq[254 - t]) : wq[127];
    coef = w * (2.0 * DPI / 255.0);
  }
  int am = (m < 0) ? -m : m;
  int l0 = (am > 1) ? am : 1;          // first valid l = max(|m|,1); written from here
  double seed;
  if (m >= 1) {
    double j = (double)m;
    double K = exp(0.5 * (lgamma(2.0 * j + 1.0) - lgamma(j) - lgamma(j + 2.0)));
    double sgn = ((m + 1) & 1) ? -1.0 : 1.0;   // (-sin)^{m+1}
    seed = sgn * K * pow(ch, j - 1.0) * pow(sh, j + 1.0);
  } else if (m <= -1) {
    double j = (double)(-m);
    double K = exp(0.5 * (lgamma(2.0 * j + 1.0) - lgamma(j) - lgamma(j + 2.0)));
    seed = K * pow(ch, j + 1.0) * pow(sh, j - 1.0);
  } else {
    seed = -sqrt(2.0) * sh * ch;       // d^1_{0,-1} = -sin(beta)/sqrt(2)
  }
  double dl = seed, dm1 = 0.0;
  for (int l = 0; l < 64; ++l) {
    float val = 0.0f;
    if (l >= l0) {
      double cl = -sqrt((2.0 * l + 1.0) / (4.0 * DPI));  // (-1)^SPIN * sqrt((2l+1)/4pi)
      val = (float)(dl * coef * cl);
      double Ld = (double)l, lp = Ld + 1.0;
      double num1 = (2.0 * Ld + 1.0) * (Ld * lp * cb + (double)m);  // -m*n with n=-1
      double num2 = lp * sqrt((Ld * Ld - (double)m * (double)m) * (Ld * Ld - 1.0));
      double den = Ld * sqrt((lp * lp - (double)m * (double)m) * (lp * lp - 1.0));
      double dn = (num1 * dl - num2 * dm1) / den;
      dm1 = dl;
      dl = dn;
    }
    out[(t * 64 + l) * 127 + mm] = val;
  }
}

// ---------------- small vector/matrix prep ----------------
__global__ void ct_tc(const float* __restrict__ temb, const float* __restrict__ trw,
                      const float* __restrict__ trb, const float* __restrict__ tiw,
                      const float* __restrict__ tib, float* tcr, float* tci) {
  int l = threadIdx.x;  // 64
  float ar = trb[l], ai = tib[l];
  for (int k = 0; k < 256; ++k) {
    float e = temb[k];
    ar = fmaf(e, trw[k * 64 + l], ar);
    ai = fmaf(e, tiw[k * 64 + l], ai);
  }
  tcr[l] = ar;
  tci[l] = ai;
}

__global__ void ct_tvec(const float* __restrict__ temb, const float* __restrict__ w,
                        const float* __restrict__ b, float* tv) {
  int j = threadIdx.x;  // 128
  float a = b[j];
  for (int k = 0; k < 256; ++k) a = fmaf(temb[k], w[k * 128 + j], a);
  tv[j] = a;
}

// A[l,i,o] = spec_conv_w[i,o] + t_c[l]*(wr+i*wi)  (complex)
__global__ void ct_A(const float* __restrict__ cw, const float* __restrict__ wr,
                     const float* __restrict__ wi, const float* __restrict__ tcr,
                     const float* __restrict__ tci, float* Ar, float* Ai) {
  int l = blockIdx.x, o = threadIdx.x;
  float tr = tcr[l], ti = tci[l];
  for (int i = 0; i < 64; ++i) {
    int idx = (l * 64 + i) * 64 + o;
    float r = wr[idx], s = wi[idx];
    Ar[idx] = cw[i * 64 + o] + tr * r - ti * s;
    Ai[idx] = tr * s + ti * r;
  }
}

// M[j,o] = w_t[o] * sum_i conv1_w[j,i]*spat_weight[i,o];  bias2[o] = w_t[o]*sum_i conv1_b[i]*sw[i,o]
__global__ void ct_M(const float* __restrict__ c1w, const float* __restrict__ c1b,
                     const float* __restrict__ sw, const float* __restrict__ tv,
                     float* M, float* bias2) {
  int j = blockIdx.x, o = threadIdx.x;
  float wt = tv[o];
  float acc = 0.f;
  for (int i = 0; i < 64; ++i) acc = fmaf(c1w[j * 64 + i], sw[i * 64 + o], acc);
  M[j * 64 + o] = wt * acc;
  if (j == 0) {
    float b = 0.f;
    for (int i = 0; i < 64; ++i) b = fmaf(c1b[i], sw[i * 64 + o], b);
    bias2[o] = wt * b;
  }
}

// ---------------- main pipeline kernels ----------------
// forward DFT over phi (255) for frequencies m=-63..63. block=(c=64), grid=t*127+mm
__global__ void ct_dft_fwd(const float* __restrict__ xin, const float* __restrict__ tw,
                           float* __restrict__ fre, float* __restrict__ fim) {
  int bid = blockIdx.x;
  int t = bid / 127, mm = bid % 127;
  int c = threadIdx.x;
  int m = mm - 63;
  int step = (m >= 0) ? m : (m + 255);
  const float* xrow = xin + (size_t)t * 255 * 64 + c;
  float ar = 0.f, ai = 0.f;
  int k = 0;
  for (int p = 0; p < 255; ++p) {
    float tc = tw[2 * k], ts = tw[2 * k + 1];
    float xv = xrow[(size_t)p * 64];
    ar = fmaf(xv, tc, ar);
    ai = fmaf(xv, ts, ai);
    k += step;
    if (k >= 255) k -= 255;
  }
  fre[(size_t)bid * 64 + c] = ar;
  fim[(size_t)bid * 64 + c] = ai;
}

// flm[l,mm,c] = sum_t Deff[t,l,mm] * ftm[t,mm,c]
__global__ void ct_proj_fwd(const float* __restrict__ D, const float* __restrict__ ire,
                            const float* __restrict__ iim, float* __restrict__ ore,
                            float* __restrict__ oim) {
  int bid = blockIdx.x;  // l*127+mm
  int l = bid / 127, mm = bid % 127;
  int c = threadIdx.x;
  float ar = 0.f, ai = 0.f;
  for (int t = 0; t < 128; ++t) {
    float d = D[(t * 64 + l) * 127 + mm];
    int idx = (t * 127 + mm) * 64 + c;
    ar = fmaf(d, ire[idx], ar);
    ai = fmaf(d, iim[idx], ai);
  }
  ore[bid * 64 + c] = ar;
  oim[bid * 64 + c] = ai;
}

// complex channel mix: out[l,mm,o] = sum_i flm[l,mm,i]*A[l,i,o] + bias[o] (bias -> real)
__global__ void ct_spec(const float* __restrict__ fre, const float* __restrict__ fim,
                        const float* __restrict__ Ar, const float* __restrict__ Ai,
                        const float* __restrict__ bias, float* __restrict__ ore,
                        float* __restrict__ oim) {
  int bid = blockIdx.x;  // l*127+mm
  int l = bid / 127;
  int o = threadIdx.x;
  float ar = bias[o], ai = 0.f;
  for (int i = 0; i < 64; ++i) {
    float fr = fre[bid * 64 + i], fi = fim[bid * 64 + i];
    int idx = (l * 64 + i) * 64 + o;
    float wr = Ar[idx], wi = Ai[idx];
    ar += fr * wr - fi * wi;
    ai += fr * wi + fi * wr;
  }
  ore[bid * 64 + o] = ar;
  oim[bid * 64 + o] = ai;
}

// ftm_out[t,mm,c] = sum_l Dinv[t,l,mm] * flm[l,mm,c]
__global__ void ct_proj_inv(const float* __restrict__ D, const float* __restrict__ ire,
                            const float* __restrict__ iim, float* __restrict__ ore,
                            float* __restrict__ oim) {
  int bid = blockIdx.x;  // t*127+mm, t<64
  int t = bid / 127, mm = bid % 127;
  int c = threadIdx.x;
  float ar = 0.f, ai = 0.f;
  for (int l = 0; l < 64; ++l) {
    float d = D[(t * 64 + l) * 127 + mm];
    int idx = (l * 127 + mm) * 64 + c;
    ar = fmaf(d, ire[idx], ar);
    ai = fmaf(d, iim[idx], ai);
  }
  ore[bid * 64 + c] = ar;
  oim[bid * 64 + c] = ai;
}

// inverse DFT (real part) over m; optional per-pixel channel L2 normalization
__global__ void ct_idft(const float* __restrict__ fre, const float* __restrict__ fim,
                        const float* __restrict__ tw, float* __restrict__ out, int do_norm) {
  int bid = blockIdx.x;  // t*127+p
  int t = bid / 127, p = bid % 127;
  int c = threadIdx.x;
  int k = (64 * p) % 127;  // m=-63 == 64 (mod 127)
  const float* fr = fre + (size_t)t * 127 * 64 + c;
  const float* fi = fim + (size_t)t * 127 * 64 + c;
  float acc = 0.f;
  for (int mm = 0; mm < 127; ++mm) {
    float tc = tw[2 * k], ts = tw[2 * k + 1];
    acc += fr[(size_t)mm * 64] * tc - fi[(size_t)mm * 64] * ts;
    k += p;
    if (k >= 127) k -= 127;
  }
  if (do_norm) {
    float ss = wave_sum64(acc * acc);
    acc = acc / (sqrtf(ss) + 1e-6f);
  }
  out[(size_t)bid * 64 + c] = acc;
}

// spatial pre-mix: h2 = x @ M + bias2
__global__ void ct_h2(const float* __restrict__ x, const float* __restrict__ M,
                      const float* __restrict__ bias2, float* __restrict__ h2) {
  int bid = blockIdx.x;  // t*255+p
  int o = threadIdx.x;
  const float* xr = x + (size_t)bid * 64;
  float acc = bias2[o];
  for (int j = 0; j < 64; ++j) acc = fmaf(xr[j], M[j * 64 + o], acc);
  h2[(size_t)bid * 64 + o] = acc;
}

// epilogue: conv2 + biases + residual + gelu + layernorm
__global__ void ct_final(const float* __restrict__ xs, const float* __restrict__ hs,
                         const float* __restrict__ c2w, const float* __restrict__ c2b,
                         const float* __restrict__ tv, const float* __restrict__ lns,
                         const float* __restrict__ lnb, float* __restrict__ out) {
  int bid = blockIdx.x;  // t*127+p
  int c = threadIdx.x;
  const float* hr = hs + (size_t)bid * 64;
  float acc = c2b[c] + tv[64 + c];  // conv2_b + b_t
  for (int i = 0; i < 64; ++i) acc = fmaf(hr[i], c2w[i * 64 + c], acc);
  float y = xs[(size_t)bid * 64 + c] + acc;
  float g = gelu_tanh(y);
  float mu = wave_sum64(g) * (1.0f / 64.0f);
  float d = g - mu;
  float var = wave_sum64(d * d) * (1.0f / 64.0f);
  out[(size_t)bid * 64 + c] = d * rsqrtf(var + 1e-6f) * lns[c] + lnb[c];
}

// ---------------- host launcher ----------------
extern "C" void kernel_launch(void* const* d_in, const int* in_sizes, int n_in,
                              void* d_out, int out_size, void* d_ws, size_t ws_size,
                              hipStream_t stream) {
  const float* x = (const float*)d_in[0];
  const float* temb = (const float*)d_in[1];
  const float* scw = (const float*)d_in[2];
  const float* scb = (const float*)d_in[3];
  const float* swr = (const float*)d_in[4];
  const float* swi = (const float*)d_in[5];
  const float* strw = (const float*)d_in[6];
  const float* strb = (const float*)d_in[7];
  const float* stiw = (const float*)d_in[8];
  const float* stib = (const float*)d_in[9];
  const float* c1w = (const float*)d_in[10];
  const float* c1b = (const float*)d_in[11];
  const float* stw = (const float*)d_in[12];
  const float* stb = (const float*)d_in[13];
  const float* sweight = (const float*)d_in[14];
  const float* c2w = (const float*)d_in[15];
  const float* c2b = (const float*)d_in[16];
  const float* lns = (const float*)d_in[17];
  const float* lnb = (const float*)d_in[18];
  float* out = (float*)d_out;

  char* base = (char*)d_ws;
  size_t off = 0;
  auto alloc = [&](size_t bytes) -> void* {
    void* p = base + off;
    off += (bytes + 255) & ~(size_t)255;
    return p;
  };
  double* wq = (double*)alloc(255 * sizeof(double));
  float* tw255 = (float*)alloc(510 * sizeof(float));
  float* tw127 = (float*)alloc(254 * sizeof(float));
  float* tcr = (float*)alloc(64 * sizeof(float));
  float* tci = (float*)alloc(64 * sizeof(float));
  float* tv = (float*)alloc(128 * sizeof(float));
  float* Mm = (float*)alloc(4096 * sizeof(float));
  float* bias2 = (float*)alloc(64 * sizeof(float));
  float* Ar = (float*)alloc(262144 * sizeof(float));
  float* Ai = (float*)alloc(262144 * sizeof(float));
  float* Deff = (float*)alloc(1040384 * sizeof(float));   // 128*64*127
  float* Dinv = (float*)alloc(520192 * sizeof(float));    // 64*64*127
  float* ftm_re = (float*)alloc(1040384 * sizeof(float)); // 128*127*64
  float* ftm_im = (float*)alloc(1040384 * sizeof(float));
  float* flm_re = (float*)alloc(520192 * sizeof(float));  // 64*127*64
  float* flm_im = (float*)alloc(520192 * sizeof(float));
  float* fl2_re = (float*)alloc(520192 * sizeof(float));
  float* fl2_im = (float*)alloc(520192 * sizeof(float));
  float* fo_re = (float*)alloc(520192 * sizeof(float));
  float* fo_im = (float*)alloc(520192 * sizeof(float));
  float* xsb = (float*)alloc(520192 * sizeof(float));
  float* hsb = (float*)alloc(520192 * sizeof(float));
  float* h2b = (float*)alloc(2088960 * sizeof(float));    // 128*255*64
  if (off > ws_size) return;  // workspace too small -> visible failure

  hipLaunchKernelGGL(ct_wq, dim3(1), dim3(256), 0, stream, wq);
  hipLaunchKernelGGL(ct_tw, dim3(1), dim3(256), 0, stream, tw255, tw127);
  hipLaunchKernelGGL(ct_wigner, dim3(127), dim3(128), 0, stream, Deff, wq, 0);
  hipLaunchKernelGGL(ct_wigner, dim3(64), dim3(128), 0, stream, Dinv, wq, 1);
  hipLaunchKernelGGL(ct_tc, dim3(1), dim3(64), 0, stream, temb, strw, strb, stiw, stib, tcr, tci);
  hipLaunchKernelGGL(ct_tvec, dim3(1), dim3(128), 0, stream, temb, stw, stb, tv);
  hipLaunchKernelGGL(ct_A, dim3(64), dim3(64), 0, stream, scw, swr, swi, tcr, tci, Ar, Ai);
  hipLaunchKernelGGL(ct_M, dim3(64), dim3(64), 0, stream, c1w, c1b, sweight, tv, Mm, bias2);

  // spectral branch
  hipLaunchKernelGGL(ct_dft_fwd, dim3(128 * 127), dim3(64), 0, stream, x, tw255, ftm_re, ftm_im);
  hipLaunchKernelGGL(ct_proj_fwd, dim3(64 * 127), dim3(64), 0, stream, Deff, ftm_re, ftm_im, flm_re, flm_im);
  hipLaunchKernelGGL(ct_spec, dim3(64 * 127), dim3(64), 0, stream, flm_re, flm_im, Ar, Ai, scb, fl2_re, fl2_im);
  hipLaunchKernelGGL(ct_proj_inv, dim3(64 * 127), dim3(64), 0, stream, Dinv, fl2_re, fl2_im, fo_re, fo_im);
  hipLaunchKernelGGL(ct_idft, dim3(64 * 127), dim3(64), 0, stream, fo_re, fo_im, tw127, xsb, 1);

  // spatial branch
  hipLaunchKernelGGL(ct_h2, dim3(128 * 255), dim3(64), 0, stream, x, Mm, bias2, h2b);
  hipLaunchKernelGGL(ct_dft_fwd, dim3(128 * 127), dim3(64), 0, stream, h2b, tw255, ftm_re, ftm_im);
  hipLaunchKernelGGL(ct_proj_fwd, dim3(64 * 127), dim3(64), 0, stream, Deff, ftm_re, ftm_im, flm_re, flm_im);
  hipLaunchKernelGGL(ct_proj_inv, dim3(64 * 127), dim3(64), 0, stream, Dinv, flm_re, flm_im, fo_re, fo_im);
  hipLaunchKernelGGL(ct_idft, dim3(64 * 127), dim3(64), 0, stream, fo_re, fo_im, tw127, hsb, 0);

  // combine + gelu + layernorm
  hipLaunchKernelGGL(ct_final, dim3(64 * 127), dim3(64), 0, stream, xsb, hsb, c2w, c2b, tv, lns, lnb, out);
}

// Round 3
// 393.118 us; speedup vs baseline: 1.3794x; 1.3794x over previous
//
#include <hip/hip_runtime.h>
#include <math.h>

#define DPI 3.141592653589793238462643383279502884

// ---------------- device helpers ----------------
__device__ __forceinline__ float wave_sum64(float v) {
#pragma unroll
  for (int off = 32; off > 0; off >>= 1) v += __shfl_xor(v, off, 64);
  return v;
}

__device__ __forceinline__ float gelu_tanh(float v) {
  float u = 0.7978845608028654f * (v + 0.044715f * v * v * v);
  return 0.5f * v * (1.0f + tanhf(u));
}

// ---------------- constant builders ----------------
// MW quadrature weights for L=128 (255 extended thetas)
__global__ void ct_wq(double* wq) {
  int t = blockIdx.x * blockDim.x + threadIdx.x;
  if (t >= 255) return;
  double th = (2.0 * t + 1.0) * DPI / 255.0;
  double s = 2.0 - DPI * sin(th);
  for (int k = 2; k <= 126; k += 2)
    s += 4.0 * cos(k * th) / (1.0 - (double)k * (double)k);
  wq[t] = s / 255.0;
}

// Wigner d^l_{m,-1}(theta) via 3-term recurrence in l (validated round 1/2).
// mode 0 (Deff, forward):  layout [t][mm][l] -> out[(t*127+mm)*64 + l], t<128
//   folded with (wq[t]+wq[254-t]) (theta-extension+parity fold), 2pi/255, CL_IN.
// mode 1 (Dinv, inverse):  layout [mm][l][t] -> out[(mm*64+l)*64 + t], t<64
//   folded with CL_OUT.
__global__ void ct_wigner(float* out, const double* wq, int mode) {
  int nth = (mode == 0) ? 128 : 64;
  int tid = blockIdx.x * blockDim.x + threadIdx.x;
  if (tid >= nth * 127) return;
  int t = tid / 127, mm = tid % 127;
  int m = mm - 63;
  double denomN = (mode == 0) ? 255.0 : 127.0;
  double beta = (2.0 * t + 1.0) * DPI / denomN;
  double cb = cos(beta);
  double ch = cos(0.5 * beta), sh = sin(0.5 * beta);
  double coef = 1.0;
  if (mode == 0) {
    double w = (t < 127) ? (wq[t] + wq[254 - t]) : wq[127];
    coef = w * (2.0 * DPI / 255.0);
  }
  int am = (m < 0) ? -m : m;
  int l0 = (am > 1) ? am : 1;
  double seed;
  if (m >= 1) {
    double j = (double)m;
    double K = exp(0.5 * (lgamma(2.0 * j + 1.0) - lgamma(j) - lgamma(j + 2.0)));
    double sgn = ((m + 1) & 1) ? -1.0 : 1.0;
    seed = sgn * K * pow(ch, j - 1.0) * pow(sh, j + 1.0);
  } else if (m <= -1) {
    double j = (double)(-m);
    double K = exp(0.5 * (lgamma(2.0 * j + 1.0) - lgamma(j) - lgamma(j + 2.0)));
    seed = K * pow(ch, j + 1.0) * pow(sh, j - 1.0);
  } else {
    seed = -sqrt(2.0) * sh * ch;
  }
  double dl = seed, dm1 = 0.0;
  for (int l = 0; l < 64; ++l) {
    float val = 0.0f;
    if (l >= l0) {
      double cl = -sqrt((2.0 * l + 1.0) / (4.0 * DPI));
      val = (float)(dl * coef * cl);
      double Ld = (double)l, lp = Ld + 1.0;
      double num1 = (2.0 * Ld + 1.0) * (Ld * lp * cb + (double)m);
      double num2 = lp * sqrt((Ld * Ld - (double)m * (double)m) * (Ld * Ld - 1.0));
      double den = Ld * sqrt((lp * lp - (double)m * (double)m) * (lp * lp - 1.0));
      double dn = (num1 * dl - num2 * dm1) / den;
      dm1 = dl;
      dl = dn;
    }
    size_t idx = (mode == 0) ? ((size_t)t * 127 + mm) * 64 + l
                             : ((size_t)mm * 64 + l) * 64 + t;
    out[idx] = val;
  }
}

// ---------------- small vector/matrix prep ----------------
__global__ void ct_tc(const float* __restrict__ temb, const float* __restrict__ trw,
                      const float* __restrict__ trb, const float* __restrict__ tiw,
                      const float* __restrict__ tib, float* tcr, float* tci) {
  int l = threadIdx.x;  // 64
  float ar = trb[l], ai = tib[l];
  for (int k = 0; k < 256; ++k) {
    float e = temb[k];
    ar = fmaf(e, trw[k * 64 + l], ar);
    ai = fmaf(e, tiw[k * 64 + l], ai);
  }
  tcr[l] = ar;
  tci[l] = ai;
}

__global__ void ct_tvec(const float* __restrict__ temb, const float* __restrict__ w,
                        const float* __restrict__ b, float* tv) {
  int j = threadIdx.x;  // 128
  float a = b[j];
  for (int k = 0; k < 256; ++k) a = fmaf(temb[k], w[k * 128 + j], a);
  tv[j] = a;
}

// A[l,i,o] = spec_conv_w[i,o] + t_c[l]*(wr+i*wi)  (complex)
__global__ void ct_A(const float* __restrict__ cw, const float* __restrict__ wr,
                     const float* __restrict__ wi, const float* __restrict__ tcr,
                     const float* __restrict__ tci, float* Ar, float* Ai) {
  int l = blockIdx.x, o = threadIdx.x;
  float tr = tcr[l], ti = tci[l];
  for (int i = 0; i < 64; ++i) {
    int idx = (l * 64 + i) * 64 + o;
    float r = wr[idx], s = wi[idx];
    Ar[idx] = cw[i * 64 + o] + tr * r - ti * s;
    Ai[idx] = tr * s + ti * r;
  }
}

// M[j,o] = w_t[o] * sum_i conv1_w[j,i]*spat_weight[i,o];  bias2[o] = w_t[o]*sum_i c1b[i]*sw[i,o]
__global__ void ct_M(const float* __restrict__ c1w, const float* __restrict__ c1b,
                     const float* __restrict__ sw, const float* __restrict__ tv,
                     float* M, float* bias2) {
  int j = blockIdx.x, o = threadIdx.x;
  float wt = tv[o];
  float acc = 0.f;
  for (int i = 0; i < 64; ++i) acc = fmaf(c1w[j * 64 + i], sw[i * 64 + o], acc);
  M[j * 64 + o] = wt * acc;
  if (j == 0) {
    float b = 0.f;
    for (int i = 0; i < 64; ++i) b = fmaf(c1b[i], sw[i * 64 + o], b);
    bias2[o] = wt * b;
  }
}

// ---------------- main pipeline ----------------
// Forward DFT over phi. lanes = mm (two halves), 16 channels/thread in regs,
// incremental rotation twiddles. Output ftm[t][mm][c].
__global__ void ct_dft(const float* __restrict__ xin,
                       float* __restrict__ fre, float* __restrict__ fim) {
  int t = blockIdx.x;          // 128
  int mmhalf = blockIdx.y;     // 2
  int c0 = blockIdx.z * 16;    // 4 chunks
  int lane = threadIdx.x;      // 64
  int mm = mmhalf * 63 + lane; // 0..126 (mm=63 duplicated, identical values)
  int m = mm - 63;
  float theta = (float)(-2.0 * DPI / 255.0) * (float)m;
  float cr, sr;
  sincosf(theta, &sr, &cr);
  float wr = 1.0f, wi = 0.0f;
  float ar[16], ai[16];
#pragma unroll
  for (int i = 0; i < 16; ++i) { ar[i] = 0.f; ai[i] = 0.f; }
  const float* xb = xin + (size_t)t * 255 * 64 + c0;
  for (int p = 0; p < 255; ++p) {
    const float4* xp = (const float4*)(xb + (size_t)p * 64);
#pragma unroll
    for (int q = 0; q < 4; ++q) {
      float4 v = xp[q];
      int i = q * 4;
      ar[i + 0] = fmaf(v.x, wr, ar[i + 0]); ai[i + 0] = fmaf(v.x, wi, ai[i + 0]);
      ar[i + 1] = fmaf(v.y, wr, ar[i + 1]); ai[i + 1] = fmaf(v.y, wi, ai[i + 1]);
      ar[i + 2] = fmaf(v.z, wr, ar[i + 2]); ai[i + 2] = fmaf(v.z, wi, ai[i + 2]);
      ar[i + 3] = fmaf(v.w, wr, ar[i + 3]); ai[i + 3] = fmaf(v.w, wi, ai[i + 3]);
    }
    float nw = wr * cr - wi * sr;
    wi = fmaf(wr, sr, wi * cr);
    wr = nw;
  }
  size_t ob = ((size_t)t * 127 + mm) * 64 + c0;
#pragma unroll
  for (int i = 0; i < 16; ++i) { fre[ob + i] = ar[i]; fim[ob + i] = ai[i]; }
}

// flm[mm][l][c] = sum_t Deff[t][mm][l] * ftm[t][mm][c]. lanes = l, 16 c/thread.
__global__ void ct_projf(const float* __restrict__ D, const float* __restrict__ fre,
                         const float* __restrict__ fim, float* __restrict__ ore,
                         float* __restrict__ oim) {
  int mm = blockIdx.x;       // 127
  int c0 = blockIdx.y * 16;  // 4
  int l = threadIdx.x;       // 64
  float ar[16], ai[16];
#pragma unroll
  for (int i = 0; i < 16; ++i) { ar[i] = 0.f; ai[i] = 0.f; }
  for (int t = 0; t < 128; ++t) {
    size_t b = ((size_t)t * 127 + mm) * 64;
    float d = D[b + l];
    const float4* fr4 = (const float4*)(fre + b + c0);
    const float4* fi4 = (const float4*)(fim + b + c0);
#pragma unroll
    for (int q = 0; q < 4; ++q) {
      float4 vr = fr4[q], vi = fi4[q];
      int i = q * 4;
      ar[i + 0] = fmaf(d, vr.x, ar[i + 0]); ai[i + 0] = fmaf(d, vi.x, ai[i + 0]);
      ar[i + 1] = fmaf(d, vr.y, ar[i + 1]); ai[i + 1] = fmaf(d, vi.y, ai[i + 1]);
      ar[i + 2] = fmaf(d, vr.z, ar[i + 2]); ai[i + 2] = fmaf(d, vi.z, ai[i + 2]);
      ar[i + 3] = fmaf(d, vr.w, ar[i + 3]); ai[i + 3] = fmaf(d, vi.w, ai[i + 3]);
    }
  }
  size_t ob = ((size_t)mm * 64 + l) * 64 + c0;
#pragma unroll
  for (int i = 0; i < 16; ++i) { ore[ob + i] = ar[i]; oim[ob + i] = ai[i]; }
}

// Fused spectral + spatial channel mixes on flm:
//   s = flm @ A_l + scb   (complex A, per-l)
//   h = flm @ M  (+ 255*S_l*bias2 at mm==63; DFT of the constant bias term)
__global__ void ct_mix(const float* __restrict__ flm_re, const float* __restrict__ flm_im,
                       const float* __restrict__ Ar, const float* __restrict__ Ai,
                       const float* __restrict__ Mm, const float* __restrict__ scb,
                       const float* __restrict__ bias2, const float* __restrict__ Deff,
                       float* __restrict__ s_re, float* __restrict__ s_im,
                       float* __restrict__ h_re, float* __restrict__ h_im) {
  __shared__ float Ash_r[4096], Ash_i[4096], Msh[4096];  // 48 KB
  int l = blockIdx.x;        // 64
  int mm0 = blockIdx.y * 4;  // 32 chunks
  int o = threadIdx.x;       // 64
  for (int k = o; k < 1024; k += 64) {
    ((float4*)Ash_r)[k] = ((const float4*)(Ar + (size_t)l * 4096))[k];
    ((float4*)Ash_i)[k] = ((const float4*)(Ai + (size_t)l * 4096))[k];
    ((float4*)Msh)[k] = ((const float4*)Mm)[k];
  }
  __syncthreads();
  float Sl = 0.f;
  if (mm0 <= 63 && 63 < mm0 + 4) {
    for (int t = 0; t < 128; ++t) Sl += Deff[((size_t)t * 127 + 63) * 64 + l];
  }
  int mmEnd = (mm0 + 4 < 127) ? mm0 + 4 : 127;
  for (int mm = mm0; mm < mmEnd; ++mm) {
    size_t ib = ((size_t)mm * 64 + l) * 64;
    float sr = scb[o], si = 0.f, hr = 0.f, hi = 0.f;
    for (int i = 0; i < 64; ++i) {
      float fr = flm_re[ib + i], fi = flm_im[ib + i];  // wave-uniform
      float war = Ash_r[i * 64 + o], wai = Ash_i[i * 64 + o];
      float wm = Msh[i * 64 + o];
      sr = fmaf(fr, war, sr); sr = fmaf(-fi, wai, sr);
      si = fmaf(fr, wai, si); si = fmaf(fi, war, si);
      hr = fmaf(fr, wm, hr);
      hi = fmaf(fi, wm, hi);
    }
    if (mm == 63) hr = fmaf(255.0f * Sl, bias2[o], hr);
    s_re[ib + o] = sr; s_im[ib + o] = si;
    h_re[ib + o] = hr; h_im[ib + o] = hi;
  }
}

// fo[t][mm][c] = sum_l Dinv[mm][l][t] * in[mm][l][c], t<64. Both branches via grid.y.
__global__ void ct_proji(const float* __restrict__ D,
                         const float* __restrict__ s_re, const float* __restrict__ s_im,
                         const float* __restrict__ h_re, const float* __restrict__ h_im,
                         float* __restrict__ os_re, float* __restrict__ os_im,
                         float* __restrict__ oh_re, float* __restrict__ oh_im) {
  __shared__ float vr[4096], vi[4096], dsh[4096];  // 48 KB
  int mm = blockIdx.x;  // 127
  int br = blockIdx.y;  // 2
  const float* ire = br ? h_re : s_re;
  const float* iim = br ? h_im : s_im;
  float* ore = br ? oh_re : os_re;
  float* oim = br ? oh_im : os_im;
  int tid = threadIdx.x;      // 256
  int w = tid >> 6, c = tid & 63;
  {
    const float4* sr4 = (const float4*)(ire + (size_t)mm * 4096);
    const float4* si4 = (const float4*)(iim + (size_t)mm * 4096);
    const float4* sd4 = (const float4*)(D + (size_t)mm * 4096);
    for (int k = tid; k < 1024; k += 256) {
      ((float4*)vr)[k] = sr4[k];
      ((float4*)vi)[k] = si4[k];
      ((float4*)dsh)[k] = sd4[k];
    }
  }
  __syncthreads();
  float ar[16], ai[16];
#pragma unroll
  for (int j = 0; j < 16; ++j) { ar[j] = 0.f; ai[j] = 0.f; }
  for (int l = 0; l < 64; ++l) {
    float fr = vr[l * 64 + c], fi = vi[l * 64 + c];
    const float4* d4 = (const float4*)(dsh + l * 64 + w * 16);
#pragma unroll
    for (int q = 0; q < 4; ++q) {
      float4 d = d4[q];
      int j = q * 4;
      ar[j + 0] = fmaf(d.x, fr, ar[j + 0]); ai[j + 0] = fmaf(d.x, fi, ai[j + 0]);
      ar[j + 1] = fmaf(d.y, fr, ar[j + 1]); ai[j + 1] = fmaf(d.y, fi, ai[j + 1]);
      ar[j + 2] = fmaf(d.z, fr, ar[j + 2]); ai[j + 2] = fmaf(d.z, fi, ai[j + 2]);
      ar[j + 3] = fmaf(d.w, fr, ar[j + 3]); ai[j + 3] = fmaf(d.w, fi, ai[j + 3]);
    }
  }
#pragma unroll
  for (int j = 0; j < 16; ++j) {
    int t = w * 16 + j;
    size_t ob = ((size_t)t * 127 + mm) * 64 + c;
    ore[ob] = ar[j];
    oim[ob] = ai[j];
  }
}

// Inverse DFT (real part) over m. lanes = p (two halves), 16 c/thread,
// rotation twiddles. Both branches via grid.z&1. No norm here (moved to final).
__global__ void ct_idft(const float* __restrict__ fs_re, const float* __restrict__ fs_im,
                        const float* __restrict__ fh_re, const float* __restrict__ fh_im,
                        float* __restrict__ xsb, float* __restrict__ hsb) {
  int t = blockIdx.x;      // 64
  int phalf = blockIdx.y;  // 2
  int z = blockIdx.z;      // 8
  int br = z & 1;
  int c0 = (z >> 1) * 16;
  int lane = threadIdx.x;
  int p = phalf * 63 + lane;  // 0..126 (p=63 duplicated)
  const float* fre = br ? fh_re : fs_re;
  const float* fim = br ? fh_im : fs_im;
  float* outp = br ? hsb : xsb;
  float delta = (float)(2.0 * DPI / 127.0) * (float)p;
  float dc, dsn;
  sincosf(delta, &dsn, &dc);
  float phi0 = delta * -63.0f;
  float wr, wi;
  sincosf(phi0, &wi, &wr);
  float acc[16];
#pragma unroll
  for (int i = 0; i < 16; ++i) acc[i] = 0.f;
  const float* fbr = fre + (size_t)t * 127 * 64 + c0;
  const float* fbi = fim + (size_t)t * 127 * 64 + c0;
  for (int mm = 0; mm < 127; ++mm) {
    const float4* r4 = (const float4*)(fbr + (size_t)mm * 64);
    const float4* i4 = (const float4*)(fbi + (size_t)mm * 64);
#pragma unroll
    for (int q = 0; q < 4; ++q) {
      float4 v = r4[q], u = i4[q];
      int i = q * 4;
      acc[i + 0] = fmaf(v.x, wr, acc[i + 0]); acc[i + 0] = fmaf(u.x, -wi, acc[i + 0]);
      acc[i + 1] = fmaf(v.y, wr, acc[i + 1]); acc[i + 1] = fmaf(u.y, -wi, acc[i + 1]);
      acc[i + 2] = fmaf(v.z, wr, acc[i + 2]); acc[i + 2] = fmaf(u.z, -wi, acc[i + 2]);
      acc[i + 3] = fmaf(v.w, wr, acc[i + 3]); acc[i + 3] = fmaf(u.w, -wi, acc[i + 3]);
    }
    float nw = wr * dc - wi * dsn;
    wi = fmaf(wr, dsn, wi * dc);
    wr = nw;
  }
  size_t ob = ((size_t)t * 127 + p) * 64 + c0;
#pragma unroll
  for (int i = 0; i < 16; ++i) outp[ob + i] = acc[i];
}

// epilogue: xs-normalize + conv2 + biases + residual + gelu + layernorm
__global__ void ct_final(const float* __restrict__ xs, const float* __restrict__ hs,
                         const float* __restrict__ c2w, const float* __restrict__ c2b,
                         const float* __restrict__ tv, const float* __restrict__ lns,
                         const float* __restrict__ lnb, float* __restrict__ out) {
  int bid = blockIdx.x;  // t*127+p
  int c = threadIdx.x;
  const float* hr = hs + (size_t)bid * 64;
  float acc = c2b[c] + tv[64 + c];
  for (int i = 0; i < 64; ++i) acc = fmaf(hr[i], c2w[i * 64 + c], acc);
  float xv = xs[(size_t)bid * 64 + c];
  float ss = wave_sum64(xv * xv);
  xv = xv / (sqrtf(ss) + 1e-6f);
  float y = xv + acc;
  float g = gelu_tanh(y);
  float mu = wave_sum64(g) * (1.0f / 64.0f);
  float d = g - mu;
  float var = wave_sum64(d * d) * (1.0f / 64.0f);
  out[(size_t)bid * 64 + c] = d * rsqrtf(var + 1e-6f) * lns[c] + lnb[c];
}

// ---------------- host launcher ----------------
extern "C" void kernel_launch(void* const* d_in, const int* in_sizes, int n_in,
                              void* d_out, int out_size, void* d_ws, size_t ws_size,
                              hipStream_t stream) {
  const float* x = (const float*)d_in[0];
  const float* temb = (const float*)d_in[1];
  const float* scw = (const float*)d_in[2];
  const float* scb = (const float*)d_in[3];
  const float* swr = (const float*)d_in[4];
  const float* swi = (const float*)d_in[5];
  const float* strw = (const float*)d_in[6];
  const float* strb = (const float*)d_in[7];
  const float* stiw = (const float*)d_in[8];
  const float* stib = (const float*)d_in[9];
  const float* c1w = (const float*)d_in[10];
  const float* c1b = (const float*)d_in[11];
  const float* stw = (const float*)d_in[12];
  const float* stb = (const float*)d_in[13];
  const float* sweight = (const float*)d_in[14];
  const float* c2w = (const float*)d_in[15];
  const float* c2b = (const float*)d_in[16];
  const float* lns = (const float*)d_in[17];
  const float* lnb = (const float*)d_in[18];
  float* out = (float*)d_out;

  char* base = (char*)d_ws;
  size_t off = 0;
  auto alloc = [&](size_t bytes) -> void* {
    void* p = base + off;
    off += (bytes + 255) & ~(size_t)255;
    return p;
  };
  double* wq = (double*)alloc(255 * sizeof(double));
  float* tcr = (float*)alloc(64 * sizeof(float));
  float* tci = (float*)alloc(64 * sizeof(float));
  float* tv = (float*)alloc(128 * sizeof(float));
  float* Mm = (float*)alloc(4096 * sizeof(float));
  float* bias2 = (float*)alloc(64 * sizeof(float));
  float* Ar = (float*)alloc(262144 * sizeof(float));
  float* Ai = (float*)alloc(262144 * sizeof(float));
  float* Deff = (float*)alloc(1040384 * sizeof(float));   // [t<128][mm][l]
  float* Dinv = (float*)alloc(520192 * sizeof(float));    // [mm][l][t<64]
  float* ftm_re = (float*)alloc(1040384 * sizeof(float)); // [t<128][mm][c]
  float* ftm_im = (float*)alloc(1040384 * sizeof(float));
  float* flm_re = (float*)alloc(520192 * sizeof(float));  // [mm][l][c]
  float* flm_im = (float*)alloc(520192 * sizeof(float));
  float* s_re = (float*)alloc(520192 * sizeof(float));
  float* s_im = (float*)alloc(520192 * sizeof(float));
  float* h_re = (float*)alloc(520192 * sizeof(float));
  float* h_im = (float*)alloc(520192 * sizeof(float));
  float* fos_re = (float*)alloc(520192 * sizeof(float));  // [t<64][mm][c]
  float* fos_im = (float*)alloc(520192 * sizeof(float));
  float* foh_re = (float*)alloc(520192 * sizeof(float));
  float* foh_im = (float*)alloc(520192 * sizeof(float));
  float* xsb = (float*)alloc(520192 * sizeof(float));
  float* hsb = (float*)alloc(520192 * sizeof(float));
  if (off > ws_size) return;  // workspace too small -> visible failure

  hipLaunchKernelGGL(ct_wq, dim3(1), dim3(256), 0, stream, wq);
  hipLaunchKernelGGL(ct_wigner, dim3(127), dim3(128), 0, stream, Deff, wq, 0);
  hipLaunchKernelGGL(ct_wigner, dim3(64), dim3(128), 0, stream, Dinv, wq, 1);
  hipLaunchKernelGGL(ct_tc, dim3(1), dim3(64), 0, stream, temb, strw, strb, stiw, stib, tcr, tci);
  hipLaunchKernelGGL(ct_tvec, dim3(1), dim3(128), 0, stream, temb, stw, stb, tv);
  hipLaunchKernelGGL(ct_A, dim3(64), dim3(64), 0, stream, scw, swr, swi, tcr, tci, Ar, Ai);
  hipLaunchKernelGGL(ct_M, dim3(64), dim3(64), 0, stream, c1w, c1b, sweight, tv, Mm, bias2);

  hipLaunchKernelGGL(ct_dft, dim3(128, 2, 4), dim3(64), 0, stream, x, ftm_re, ftm_im);
  hipLaunchKernelGGL(ct_projf, dim3(127, 4), dim3(64), 0, stream, Deff, ftm_re, ftm_im, flm_re, flm_im);
  hipLaunchKernelGGL(ct_mix, dim3(64, 32), dim3(64), 0, stream, flm_re, flm_im, Ar, Ai, Mm,
                     scb, bias2, Deff, s_re, s_im, h_re, h_im);
  hipLaunchKernelGGL(ct_proji, dim3(127, 2), dim3(256), 0, stream, Dinv, s_re, s_im, h_re, h_im,
                     fos_re, fos_im, foh_re, foh_im);
  hipLaunchKernelGGL(ct_idft, dim3(64, 2, 8), dim3(64), 0, stream, fos_re, fos_im, foh_re, foh_im,
                     xsb, hsb);
  hipLaunchKernelGGL(ct_final, dim3(64 * 127), dim3(64), 0, stream, xsb, hsb, c2w, c2b, tv, lns, lnb, out);
}

// Round 4
// 291.793 us; speedup vs baseline: 1.8585x; 1.3472x over previous
//
#include <hip/hip_runtime.h>
#include <math.h>

#define DPI 3.141592653589793238462643383279502884

// ---------------- device helpers ----------------
__device__ __forceinline__ float wave_sum64(float v) {
#pragma unroll
  for (int off = 32; off > 0; off >>= 1) v += __shfl_xor(v, off, 64);
  return v;
}

__device__ __forceinline__ float gelu_tanh(float v) {
  float u = 0.7978845608028654f * (v + 0.044715f * v * v * v);
  return 0.5f * v * (1.0f + tanhf(u));
}

// ---------------- constants: Wigner-d tables (wq folded in) ----------------
// mode 0 (blocks 0..127): Deff[t][mm][l], t=blockIdx, lanes=mm.
//   coef = (wq[t]+wq[254-t]) * 2pi/255 via pair identity
//   (wq[t]+wq[254-t]) = (4 + sum_{k even>=2} 8 cos(k*th)/(1-k^2))/255; t=127 -> half.
// mode 1 (blocks 128..254): Dinv[mm][l][t], mm=blockIdx-128, lanes=t (coalesced stores).
__global__ void ct_wigner(float* __restrict__ Deff, float* __restrict__ Dinv) {
  __shared__ float clf[64];
  int b = blockIdx.x;
  int mode = (b < 128) ? 0 : 1;
  if (threadIdx.x < 64)
    clf[threadIdx.x] = (float)(-sqrt((2.0 * threadIdx.x + 1.0) / (4.0 * DPI)));
  __syncthreads();
  int t, mm;
  if (mode == 0) {
    t = b; mm = threadIdx.x;
    if (mm >= 127) return;
  } else {
    mm = b - 128; t = threadIdx.x;
    if (t >= 64) return;
  }
  int m = mm - 63;
  double denomN = (mode == 0) ? 255.0 : 127.0;
  double beta = (2.0 * t + 1.0) * DPI / denomN;
  double cb = cos(beta);
  double ch = cos(0.5 * beta), sh = sin(0.5 * beta);
  double coef = 1.0;
  if (mode == 0) {
    double s = 4.0;
    for (int k = 2; k <= 126; k += 2)
      s += 8.0 * cos((double)k * beta) / (1.0 - (double)k * (double)k);
    s /= 255.0;
    if (t == 127) s *= 0.5;
    coef = s * (2.0 * DPI / 255.0);
  }
  int am = (m < 0) ? -m : m;
  int l0v = (am > 1) ? am : 1;
  double seed;
  if (m >= 1) {
    double j = (double)m;
    double K = exp(0.5 * (lgamma(2.0 * j + 1.0) - lgamma(j) - lgamma(j + 2.0)));
    double sgn = ((m + 1) & 1) ? -1.0 : 1.0;
    seed = sgn * K * pow(ch, j - 1.0) * pow(sh, j + 1.0);
  } else if (m <= -1) {
    double j = (double)(-m);
    double K = exp(0.5 * (lgamma(2.0 * j + 1.0) - lgamma(j) - lgamma(j + 2.0)));
    seed = K * pow(ch, j + 1.0) * pow(sh, j - 1.0);
  } else {
    seed = -sqrt(2.0) * sh * ch;
  }
  double dl = seed, dm1 = 0.0, S_cur = 0.0;  // S(l0)=0 exactly
  for (int l = 0; l < 64; ++l) {
    float val = 0.0f;
    if (l >= l0v) {
      val = (float)(dl * coef) * clf[l];
      double Ld = (double)l, lp = Ld + 1.0;
      double S_next = sqrt((lp * lp - (double)m * (double)m) * (lp * lp - 1.0));
      double num1 = (2.0 * Ld + 1.0) * (Ld * lp * cb + (double)m);
      double dn = (num1 * dl - lp * S_cur * dm1) / (Ld * S_next);
      dm1 = dl; dl = dn; S_cur = S_next;
    }
    if (mode == 0) Deff[((size_t)t * 127 + mm) * 64 + l] = val;
    else Dinv[((size_t)mm * 64 + l) * 64 + t] = val;
  }
}

// ---------------- prep: t-embedding projections ----------------
__global__ void ct_prep(const float* __restrict__ temb,
                        const float* __restrict__ trw, const float* __restrict__ trb,
                        const float* __restrict__ tiw, const float* __restrict__ tib,
                        const float* __restrict__ stw, const float* __restrict__ stb,
                        float* tcr, float* tci, float* tv) {
  int i = threadIdx.x;  // 192
  if (i < 64) {
    float ar = trb[i], ai = tib[i];
    for (int k = 0; k < 256; ++k) {
      float e = temb[k];
      ar = fmaf(e, trw[k * 64 + i], ar);
      ai = fmaf(e, tiw[k * 64 + i], ai);
    }
    tcr[i] = ar; tci[i] = ai;
  } else {
    int j = i - 64;
    float a = stb[j];
    for (int k = 0; k < 256; ++k) a = fmaf(temb[k], stw[k * 128 + j], a);
    tv[j] = a;
  }
}

// A2[l][i][o] = {conv_w + tr*wr - ti*wi, tr*wi + ti*wr};  M[j][o]; bias2[o]
__global__ void ct_AM(const float* __restrict__ cw, const float* __restrict__ wr,
                      const float* __restrict__ wi, const float* __restrict__ tcr,
                      const float* __restrict__ tci, const float* __restrict__ c1w,
                      const float* __restrict__ c1b, const float* __restrict__ sw,
                      const float* __restrict__ tv, float2* __restrict__ A2,
                      float* __restrict__ Mm, float* __restrict__ bias2) {
  int b = blockIdx.x, o = threadIdx.x;
  if (b < 64) {
    int l = b;
    float tr = tcr[l], ti = tci[l];
    for (int i = 0; i < 64; ++i) {
      int idx = (l * 64 + i) * 64 + o;
      float r = wr[idx], s = wi[idx];
      A2[idx] = make_float2(cw[i * 64 + o] + tr * r - ti * s, tr * s + ti * r);
    }
  } else {
    int j = b - 64;
    float wt = tv[o];
    float acc = 0.f;
    for (int i = 0; i < 64; ++i) acc = fmaf(c1w[j * 64 + i], sw[i * 64 + o], acc);
    Mm[j * 64 + o] = wt * acc;
    if (j == 0) {
      float bb = 0.f;
      for (int i = 0; i < 64; ++i) bb = fmaf(c1b[i], sw[i * 64 + o], bb);
      bias2[o] = wt * bb;
    }
  }
}

// ---------------- forward DFT (split-p, dual twiddle chains, pipelined) ----------------
// grid (t=128, mmhalf=2, z=8: ph=z&1, c0=(z>>1)*16); block 64 (lane=mm).
// ph=0 sums p 0..127 -> ftmA; ph=1 sums p 128..254 -> ftmB.
__global__ void ct_dft(const float* __restrict__ xin,
                       float* __restrict__ freA, float* __restrict__ fimA,
                       float* __restrict__ freB, float* __restrict__ fimB) {
  int t = blockIdx.x;
  int mmhalf = blockIdx.y;
  int ph = blockIdx.z & 1;
  int c0 = (blockIdx.z >> 1) * 16;
  int lane = threadIdx.x;
  int mm = mmhalf * 63 + lane;
  int m = mm - 63;
  int pstart = ph * 128;
  int n = 128 - ph;  // 128 or 127
  float* fre = ph ? freB : freA;
  float* fim = ph ? fimB : fimA;
  float delta = (float)(-2.0 * DPI / 255.0) * (float)m;
  float s2c, s2s;
  sincosf(2.0f * delta, &s2s, &s2c);
  float w0r, w0i, w1r, w1i;
  sincosf(delta * (float)pstart, &w0i, &w0r);
  sincosf(delta * (float)(pstart + 1), &w1i, &w1r);
  float ar[16], ai[16];
#pragma unroll
  for (int i = 0; i < 16; ++i) { ar[i] = 0.f; ai[i] = 0.f; }
  const float* xb = xin + ((size_t)t * 255 + pstart) * 64 + c0;
  float4 ca[4], cbv[4], na[4], nb[4];
#define LD4(dst, p_)                                                  \
  {                                                                   \
    const float4* q_ = (const float4*)(xb + (size_t)(p_) * 64);       \
    dst[0] = q_[0]; dst[1] = q_[1]; dst[2] = q_[2]; dst[3] = q_[3];   \
  }
#define ACC4(src, wR, wI)                                                      \
  _Pragma("unroll") for (int q_ = 0; q_ < 4; ++q_) {                           \
    float4 v_ = src[q_];                                                       \
    int i_ = q_ * 4;                                                           \
    ar[i_ + 0] = fmaf(v_.x, wR, ar[i_ + 0]); ai[i_ + 0] = fmaf(v_.x, wI, ai[i_ + 0]); \
    ar[i_ + 1] = fmaf(v_.y, wR, ar[i_ + 1]); ai[i_ + 1] = fmaf(v_.y, wI, ai[i_ + 1]); \
    ar[i_ + 2] = fmaf(v_.z, wR, ar[i_ + 2]); ai[i_ + 2] = fmaf(v_.z, wI, ai[i_ + 2]); \
    ar[i_ + 3] = fmaf(v_.w, wR, ar[i_ + 3]); ai[i_ + 3] = fmaf(v_.w, wI, ai[i_ + 3]); \
  }
#define STEP0 { float t_ = w0r * s2c - w0i * s2s; w0i = fmaf(w0r, s2s, w0i * s2c); w0r = t_; }
#define STEP1 { float t_ = w1r * s2c - w1i * s2s; w1i = fmaf(w1r, s2s, w1i * s2c); w1r = t_; }
  LD4(ca, 0);
  LD4(cbv, 1);
  int i = 0;
  for (; i + 4 <= n; i += 4) {
    LD4(na, i + 2);
    LD4(nb, i + 3);
    ACC4(ca, w0r, w0i); STEP0;
    ACC4(cbv, w1r, w1i); STEP1;
    int r0 = (i + 4 <= n - 1) ? i + 4 : n - 1;
    int r1 = (i + 5 <= n - 1) ? i + 5 : n - 1;
    LD4(ca, r0);
    LD4(cbv, r1);
    ACC4(na, w0r, w0i); STEP0;
    ACC4(nb, w1r, w1i); STEP1;
  }
  if (i < n) { ACC4(ca, w0r, w0i); }
  if (i + 1 < n) { ACC4(cbv, w1r, w1i); }
  if (i + 2 < n) { STEP0; LD4(na, i + 2); ACC4(na, w0r, w0i); }
#undef LD4
#undef ACC4
#undef STEP0
#undef STEP1
  size_t ob = ((size_t)t * 127 + mm) * 64 + c0;
  float4* fr4 = (float4*)(fre + ob);
  float4* fi4 = (float4*)(fim + ob);
#pragma unroll
  for (int q = 0; q < 4; ++q) {
    fr4[q] = make_float4(ar[q * 4], ar[q * 4 + 1], ar[q * 4 + 2], ar[q * 4 + 3]);
    fi4[q] = make_float4(ai[q * 4], ai[q * 4 + 1], ai[q * 4 + 2], ai[q * 4 + 3]);
  }
}

// ---------------- forward projection (lane=c, register l-tile, t-split) ----------------
// grid (mm=127, lq=4, th=2); block 64. out: flm{A,B}[mm][l][c] interleaved float2.
__global__ void ct_projf(const float* __restrict__ D,
                         const float* __restrict__ fAre, const float* __restrict__ fAim,
                         const float* __restrict__ fBre, const float* __restrict__ fBim,
                         float2* __restrict__ flmA, float2* __restrict__ flmB) {
  int mm = blockIdx.x;
  int l0 = blockIdx.y * 16;
  int th = blockIdx.z;
  int c = threadIdx.x;
  float2* outp = th ? flmB : flmA;
  float ar[16], ai[16];
#pragma unroll
  for (int j = 0; j < 16; ++j) { ar[j] = 0.f; ai[j] = 0.f; }
  int tb = th * 64;
#pragma unroll 2
  for (int tt = 0; tt < 64; ++tt) {
    size_t bidx = ((size_t)(tb + tt) * 127 + mm) * 64;
    float fr = fAre[bidx + c] + fBre[bidx + c];
    float fi = fAim[bidx + c] + fBim[bidx + c];
    const float4* d4 = (const float4*)(D + bidx + l0);
#pragma unroll
    for (int q = 0; q < 4; ++q) {
      float4 d = d4[q];
      int j = q * 4;
      ar[j + 0] = fmaf(d.x, fr, ar[j + 0]); ai[j + 0] = fmaf(d.x, fi, ai[j + 0]);
      ar[j + 1] = fmaf(d.y, fr, ar[j + 1]); ai[j + 1] = fmaf(d.y, fi, ai[j + 1]);
      ar[j + 2] = fmaf(d.z, fr, ar[j + 2]); ai[j + 2] = fmaf(d.z, fi, ai[j + 2]);
      ar[j + 3] = fmaf(d.w, fr, ar[j + 3]); ai[j + 3] = fmaf(d.w, fi, ai[j + 3]);
    }
  }
#pragma unroll
  for (int j = 0; j < 16; ++j)
    outp[((size_t)mm * 64 + (l0 + j)) * 64 + c] = make_float2(ar[j], ai[j]);
}

// ---------------- fused channel mixes (no LDS, 4-mm register tile) ----------------
// grid (l=64, chunk=32); block 64 (lane=o).
__global__ void ct_mix(const float2* __restrict__ flmA, const float2* __restrict__ flmB,
                       const float2* __restrict__ A2, const float* __restrict__ Mm,
                       const float* __restrict__ scb, const float* __restrict__ bias2,
                       const float* __restrict__ Deff,
                       float2* __restrict__ s2, float2* __restrict__ h2) {
  int l = blockIdx.x;
  int mm0 = blockIdx.y * 4;
  int o = threadIdx.x;
  float sr[4], si[4], hr[4], hi[4];
  float b0 = scb[o];
  size_t ib[4];
#pragma unroll
  for (int j = 0; j < 4; ++j) {
    int mmj = (mm0 + j < 127) ? mm0 + j : 126;
    ib[j] = ((size_t)mmj * 64 + l) * 64;
    sr[j] = b0; si[j] = 0.f; hr[j] = 0.f; hi[j] = 0.f;
  }
  const float2* Abase = A2 + (size_t)l * 4096;
#pragma unroll 2
  for (int i = 0; i < 64; ++i) {
    float2 w2 = Abase[(size_t)i * 64 + o];
    float wm = Mm[i * 64 + o];
#pragma unroll
    for (int j = 0; j < 4; ++j) {
      float2 fa = flmA[ib[j] + i];
      float2 fb = flmB[ib[j] + i];
      float fr = fa.x + fb.x, fi = fa.y + fb.y;
      sr[j] = fmaf(fr, w2.x, sr[j]); sr[j] = fmaf(-fi, w2.y, sr[j]);
      si[j] = fmaf(fr, w2.y, si[j]); si[j] = fmaf(fi, w2.x, si[j]);
      hr[j] = fmaf(fr, wm, hr[j]);
      hi[j] = fmaf(fi, wm, hi[j]);
    }
  }
  if (mm0 <= 63 && 63 < mm0 + 4) {  // DFT of constant bias2 -> pure m=0 (mm=63) spike
    float Sl = 0.f;
    for (int tt = 0; tt < 128; ++tt) Sl += Deff[((size_t)tt * 127 + 63) * 64 + l];
    int j = 63 - mm0;
    hr[j] = fmaf(255.0f * Sl, bias2[o], hr[j]);
  }
#pragma unroll
  for (int j = 0; j < 4; ++j) {
    if (mm0 + j < 127) {
      s2[ib[j] + o] = make_float2(sr[j], si[j]);
      h2[ib[j] + o] = make_float2(hr[j], hi[j]);
    }
  }
}

// ---------------- inverse projection ----------------
// grid (mm=127, br=2); block 256 (w=t-quad, c=lane). fo[t][mm][c] float2.
__global__ void ct_proji(const float* __restrict__ D, const float2* __restrict__ s2,
                         const float2* __restrict__ h2, float2* __restrict__ fo_s,
                         float2* __restrict__ fo_h) {
  __shared__ float2 v2[4096];
  __shared__ float dsh[4096];
  int mm = blockIdx.x;
  int br = blockIdx.y;
  const float2* in2 = br ? h2 : s2;
  float2* out2 = br ? fo_h : fo_s;
  int tid = threadIdx.x;
  int w = tid >> 6, c = tid & 63;
  {
    const float4* s4 = (const float4*)(in2 + (size_t)mm * 4096);
    float4* v4 = (float4*)v2;
    for (int k = tid; k < 2048; k += 256) v4[k] = s4[k];
    const float4* d4s = (const float4*)(D + (size_t)mm * 4096);
    float4* d4d = (float4*)dsh;
    for (int k = tid; k < 1024; k += 256) d4d[k] = d4s[k];
  }
  __syncthreads();
  float ar[16], ai[16];
#pragma unroll
  for (int j = 0; j < 16; ++j) { ar[j] = 0.f; ai[j] = 0.f; }
#pragma unroll 2
  for (int l = 0; l < 64; ++l) {
    float2 f = v2[l * 64 + c];
    const float4* d4 = (const float4*)(dsh + l * 64 + w * 16);
#pragma unroll
    for (int q = 0; q < 4; ++q) {
      float4 d = d4[q];
      int j = q * 4;
      ar[j + 0] = fmaf(d.x, f.x, ar[j + 0]); ai[j + 0] = fmaf(d.x, f.y, ai[j + 0]);
      ar[j + 1] = fmaf(d.y, f.x, ar[j + 1]); ai[j + 1] = fmaf(d.y, f.y, ai[j + 1]);
      ar[j + 2] = fmaf(d.z, f.x, ar[j + 2]); ai[j + 2] = fmaf(d.z, f.y, ai[j + 2]);
      ar[j + 3] = fmaf(d.w, f.x, ar[j + 3]); ai[j + 3] = fmaf(d.w, f.y, ai[j + 3]);
    }
  }
#pragma unroll
  for (int j = 0; j < 16; ++j) {
    int t = w * 16 + j;
    out2[((size_t)t * 127 + mm) * 64 + c] = make_float2(ar[j], ai[j]);
  }
}

// ---------------- inverse DFT (dual chains, pipelined) ----------------
// grid (t=64, phalf=2, z=8: br=z&1, c0=(z>>1)*16); block 64 (lane=p).
__global__ void ct_idft(const float2* __restrict__ fo_s, const float2* __restrict__ fo_h,
                        float* __restrict__ xsb, float* __restrict__ hsb) {
  int t = blockIdx.x;
  int phalf = blockIdx.y;
  int z = blockIdx.z;
  int br = z & 1;
  int c0 = (z >> 1) * 16;
  int lane = threadIdx.x;
  int p = phalf * 63 + lane;
  const float2* fo = br ? fo_h : fo_s;
  float* outp = br ? hsb : xsb;
  float delta = (float)(2.0 * DPI / 127.0) * (float)p;
  float s2c, s2s;
  sincosf(2.0f * delta, &s2s, &s2c);
  float w0r, w0i, w1r, w1i;
  sincosf(delta * -63.0f, &w0i, &w0r);
  sincosf(delta * -62.0f, &w1i, &w1r);
  float acc[16];
#pragma unroll
  for (int i = 0; i < 16; ++i) acc[i] = 0.f;
  const float2* fb = fo + (size_t)t * 127 * 64 + c0;
  float4 ca[8], cbv[8], na[8], nb[8];
#define LDI(dst, mm_)                                             \
  {                                                               \
    const float4* q_ = (const float4*)(fb + (size_t)(mm_) * 64);  \
    _Pragma("unroll") for (int q2 = 0; q2 < 8; ++q2) dst[q2] = q_[q2]; \
  }
#define ACCI(src, wR, wI)                                         \
  _Pragma("unroll") for (int q_ = 0; q_ < 8; ++q_) {              \
    float4 v_ = src[q_];                                          \
    acc[2 * q_] = fmaf(v_.x, wR, acc[2 * q_]);                    \
    acc[2 * q_] = fmaf(v_.y, -(wI), acc[2 * q_]);                 \
    acc[2 * q_ + 1] = fmaf(v_.z, wR, acc[2 * q_ + 1]);            \
    acc[2 * q_ + 1] = fmaf(v_.w, -(wI), acc[2 * q_ + 1]);         \
  }
#define STEP0 { float t_ = w0r * s2c - w0i * s2s; w0i = fmaf(w0r, s2s, w0i * s2c); w0r = t_; }
#define STEP1 { float t_ = w1r * s2c - w1i * s2s; w1i = fmaf(w1r, s2s, w1i * s2c); w1r = t_; }
  const int n = 127;
  LDI(ca, 0);
  LDI(cbv, 1);
  int i = 0;
  for (; i + 4 <= n; i += 4) {
    LDI(na, i + 2);
    LDI(nb, i + 3);
    ACCI(ca, w0r, w0i); STEP0;
    ACCI(cbv, w1r, w1i); STEP1;
    int r0 = (i + 4 <= n - 1) ? i + 4 : n - 1;
    int r1 = (i + 5 <= n - 1) ? i + 5 : n - 1;
    LDI(ca, r0);
    LDI(cbv, r1);
    ACCI(na, w0r, w0i); STEP0;
    ACCI(nb, w1r, w1i); STEP1;
  }
  if (i < n) { ACCI(ca, w0r, w0i); }
  if (i + 1 < n) { ACCI(cbv, w1r, w1i); }
  if (i + 2 < n) { STEP0; LDI(na, i + 2); ACCI(na, w0r, w0i); }
#undef LDI
#undef ACCI
#undef STEP0
#undef STEP1
  size_t ob = ((size_t)t * 127 + p) * 64 + c0;
#pragma unroll
  for (int q = 0; q < 4; ++q)
    ((float4*)(outp + ob))[q] =
        make_float4(acc[q * 4], acc[q * 4 + 1], acc[q * 4 + 2], acc[q * 4 + 3]);
}

// ---------------- epilogue ----------------
__global__ void ct_final(const float* __restrict__ xs, const float* __restrict__ hs,
                         const float* __restrict__ c2w, const float* __restrict__ c2b,
                         const float* __restrict__ tv, const float* __restrict__ lns,
                         const float* __restrict__ lnb, float* __restrict__ out) {
  int bid = blockIdx.x;  // t*127+p
  int c = threadIdx.x;
  const float* hr = hs + (size_t)bid * 64;
  float acc = c2b[c] + tv[64 + c];
#pragma unroll 4
  for (int i = 0; i < 64; ++i) acc = fmaf(hr[i], c2w[i * 64 + c], acc);
  float xv = xs[(size_t)bid * 64 + c];
  float ss = wave_sum64(xv * xv);
  xv = xv / (sqrtf(ss) + 1e-6f);
  float y = xv + acc;
  float g = gelu_tanh(y);
  float mu = wave_sum64(g) * (1.0f / 64.0f);
  float d = g - mu;
  float var = wave_sum64(d * d) * (1.0f / 64.0f);
  out[(size_t)bid * 64 + c] = d * rsqrtf(var + 1e-6f) * lns[c] + lnb[c];
}

// ---------------- host launcher ----------------
extern "C" void kernel_launch(void* const* d_in, const int* in_sizes, int n_in,
                              void* d_out, int out_size, void* d_ws, size_t ws_size,
                              hipStream_t stream) {
  const float* x = (const float*)d_in[0];
  const float* temb = (const float*)d_in[1];
  const float* scw = (const float*)d_in[2];
  const float* scb = (const float*)d_in[3];
  const float* swr = (const float*)d_in[4];
  const float* swi = (const float*)d_in[5];
  const float* strw = (const float*)d_in[6];
  const float* strb = (const float*)d_in[7];
  const float* stiw = (const float*)d_in[8];
  const float* stib = (const float*)d_in[9];
  const float* c1w = (const float*)d_in[10];
  const float* c1b = (const float*)d_in[11];
  const float* stw = (const float*)d_in[12];
  const float* stb = (const float*)d_in[13];
  const float* sweight = (const float*)d_in[14];
  const float* c2w = (const float*)d_in[15];
  const float* c2b = (const float*)d_in[16];
  const float* lns = (const float*)d_in[17];
  const float* lnb = (const float*)d_in[18];
  float* out = (float*)d_out;

  char* base = (char*)d_ws;
  size_t off = 0;
  auto alloc = [&](size_t bytes) -> void* {
    void* p = base + off;
    off += (bytes + 255) & ~(size_t)255;
    return p;
  };
  float* tcr = (float*)alloc(64 * sizeof(float));
  float* tci = (float*)alloc(64 * sizeof(float));
  float* tv = (float*)alloc(128 * sizeof(float));
  float* Mm = (float*)alloc(4096 * sizeof(float));
  float* bias2 = (float*)alloc(64 * sizeof(float));
  float2* A2 = (float2*)alloc(262144 * sizeof(float2));
  float* Deff = (float*)alloc(1040384 * sizeof(float));  // [t<128][mm][l]
  float* Dinv = (float*)alloc(520192 * sizeof(float));   // [mm][l][t<64]
  float* ftmA_re = (float*)alloc(1040384 * sizeof(float));
  float* ftmA_im = (float*)alloc(1040384 * sizeof(float));
  float* ftmB_re = (float*)alloc(1040384 * sizeof(float));
  float* ftmB_im = (float*)alloc(1040384 * sizeof(float));
  float2* flmA = (float2*)alloc(520192 * sizeof(float2));
  float2* flmB = (float2*)alloc(520192 * sizeof(float2));
  // aliases (lifetimes disjoint across launches):
  float2* s2 = (float2*)ftmA_re;   // 4.16 MB each, exact fit
  float2* h2 = (float2*)ftmA_im;
  float2* fo_s = (float2*)ftmB_re;
  float2* fo_h = (float2*)ftmB_im;
  float* xsb = (float*)flmA;       // 2.08 MB needed <= 4.16
  float* hsb = (float*)flmB;
  if (off > ws_size) return;  // workspace too small -> visible failure

  hipLaunchKernelGGL(ct_prep, dim3(1), dim3(192), 0, stream, temb, strw, strb, stiw, stib,
                     stw, stb, tcr, tci, tv);
  hipLaunchKernelGGL(ct_wigner, dim3(255), dim3(128), 0, stream, Deff, Dinv);
  hipLaunchKernelGGL(ct_AM, dim3(128), dim3(64), 0, stream, scw, swr, swi, tcr, tci,
                     c1w, c1b, sweight, tv, A2, Mm, bias2);
  hipLaunchKernelGGL(ct_dft, dim3(128, 2, 8), dim3(64), 0, stream, x,
                     ftmA_re, ftmA_im, ftmB_re, ftmB_im);
  hipLaunchKernelGGL(ct_projf, dim3(127, 4, 2), dim3(64), 0, stream, Deff,
                     ftmA_re, ftmA_im, ftmB_re, ftmB_im, flmA, flmB);
  hipLaunchKernelGGL(ct_mix, dim3(64, 32), dim3(64), 0, stream, flmA, flmB, A2, Mm,
                     scb, bias2, Deff, s2, h2);
  hipLaunchKernelGGL(ct_proji, dim3(127, 2), dim3(256), 0, stream, Dinv, s2, h2, fo_s, fo_h);
  hipLaunchKernelGGL(ct_idft, dim3(64, 2, 8), dim3(64), 0, stream, fo_s, fo_h, xsb, hsb);
  hipLaunchKernelGGL(ct_final, dim3(8128), dim3(64), 0, stream, xsb, hsb, c2w, c2b, tv,
                     lns, lnb, out);
}

// Round 5
// 274.995 us; speedup vs baseline: 1.9720x; 1.0611x over previous
//
#include <hip/hip_runtime.h>
#include <math.h>

#define DPI 3.141592653589793238462643383279502884

// ---------------- device helpers ----------------
__device__ __forceinline__ float wave_sum64(float v) {
#pragma unroll
  for (int off = 32; off > 0; off >>= 1) v += __shfl_xor(v, off, 64);
  return v;
}

__device__ __forceinline__ float gelu_tanh(float v) {
  float u = 0.7978845608028654f * (v + 0.044715f * v * v * v);
  return 0.5f * v * (1.0f + tanhf(u));
}

// ---------------- constants: Wigner-d tables (wq folded in) ----------------
// mode 0 (blocks 0..127): Deff[t][mm][l], t=blockIdx, lanes=mm.
// mode 1 (blocks 128..254): Dinv[mm][l][t], mm=blockIdx-128, lanes=t.
__global__ void ct_wigner(float* __restrict__ Deff, float* __restrict__ Dinv) {
  __shared__ float clf[64];
  int b = blockIdx.x;
  int mode = (b < 128) ? 0 : 1;
  if (threadIdx.x < 64)
    clf[threadIdx.x] = (float)(-sqrt((2.0 * threadIdx.x + 1.0) / (4.0 * DPI)));
  __syncthreads();
  int t, mm;
  if (mode == 0) {
    t = b; mm = threadIdx.x;
    if (mm >= 127) return;
  } else {
    mm = b - 128; t = threadIdx.x;
    if (t >= 64) return;
  }
  int m = mm - 63;
  double denomN = (mode == 0) ? 255.0 : 127.0;
  double beta = (2.0 * t + 1.0) * DPI / denomN;
  double cb = cos(beta);
  double ch = cos(0.5 * beta), sh = sin(0.5 * beta);
  double coef = 1.0;
  if (mode == 0) {
    double s = 4.0;
    for (int k = 2; k <= 126; k += 2)
      s += 8.0 * cos((double)k * beta) / (1.0 - (double)k * (double)k);
    s /= 255.0;
    if (t == 127) s *= 0.5;
    coef = s * (2.0 * DPI / 255.0);
  }
  int am = (m < 0) ? -m : m;
  int l0v = (am > 1) ? am : 1;
  double seed;
  if (m >= 1) {
    double j = (double)m;
    double K = exp(0.5 * (lgamma(2.0 * j + 1.0) - lgamma(j) - lgamma(j + 2.0)));
    double sgn = ((m + 1) & 1) ? -1.0 : 1.0;
    seed = sgn * K * pow(ch, j - 1.0) * pow(sh, j + 1.0);
  } else if (m <= -1) {
    double j = (double)(-m);
    double K = exp(0.5 * (lgamma(2.0 * j + 1.0) - lgamma(j) - lgamma(j + 2.0)));
    seed = K * pow(ch, j + 1.0) * pow(sh, j - 1.0);
  } else {
    seed = -sqrt(2.0) * sh * ch;
  }
  double dl = seed, dm1 = 0.0, S_cur = 0.0;
  for (int l = 0; l < 64; ++l) {
    float val = 0.0f;
    if (l >= l0v) {
      val = (float)(dl * coef) * clf[l];
      double Ld = (double)l, lp = Ld + 1.0;
      double S_next = sqrt((lp * lp - (double)m * (double)m) * (lp * lp - 1.0));
      double num1 = (2.0 * Ld + 1.0) * (Ld * lp * cb + (double)m);
      double dn = (num1 * dl - lp * S_cur * dm1) / (Ld * S_next);
      dm1 = dl; dl = dn; S_cur = S_next;
    }
    if (mode == 0) Deff[((size_t)t * 127 + mm) * 64 + l] = val;
    else Dinv[((size_t)mm * 64 + l) * 64 + t] = val;
  }
}

// ---------------- twiddle tables ----------------
// T255[p][mm] = (cos(2pi m p/255), -sin(...)), m=mm-63   (forward)
// T127[mm][p] = (cos(2pi m p/127),  sin(...)), m=mm-63   (inverse; acc += fr*c - fi*s)
__global__ void ct_tw2(float2* __restrict__ T255, float2* __restrict__ T127) {
  int id = blockIdx.x * 256 + threadIdx.x;
  if (id < 255 * 127) {
    int p = id / 127, mm = id % 127;
    double ang = 2.0 * DPI * (double)((mm - 63) * p) / 255.0;
    T255[id] = make_float2((float)cos(ang), (float)(-sin(ang)));
  }
  if (id < 127 * 127) {
    int mm = id / 127, p = id % 127;
    double ang = 2.0 * DPI * (double)((mm - 63) * p) / 127.0;
    T127[id] = make_float2((float)cos(ang), (float)sin(ang));
  }
}

// ---------------- prep: t-embedding projections ----------------
__global__ void ct_prep(const float* __restrict__ temb,
                        const float* __restrict__ trw, const float* __restrict__ trb,
                        const float* __restrict__ tiw, const float* __restrict__ tib,
                        const float* __restrict__ stw, const float* __restrict__ stb,
                        float* tcr, float* tci, float* tv) {
  int i = threadIdx.x;  // 192
  if (i < 64) {
    float ar = trb[i], ai = tib[i];
    for (int k = 0; k < 256; ++k) {
      float e = temb[k];
      ar = fmaf(e, trw[k * 64 + i], ar);
      ai = fmaf(e, tiw[k * 64 + i], ai);
    }
    tcr[i] = ar; tci[i] = ai;
  } else {
    int j = i - 64;
    float a = stb[j];
    for (int k = 0; k < 256; ++k) a = fmaf(temb[k], stw[k * 128 + j], a);
    tv[j] = a;
  }
}

// A2[l][i][o]; M[j][o]; bias2[o]; Sl[l] = sum_t Deff[t][63][l]
__global__ void ct_AM(const float* __restrict__ cw, const float* __restrict__ wr,
                      const float* __restrict__ wi, const float* __restrict__ tcr,
                      const float* __restrict__ tci, const float* __restrict__ c1w,
                      const float* __restrict__ c1b, const float* __restrict__ sw,
                      const float* __restrict__ tv, const float* __restrict__ Deff,
                      float2* __restrict__ A2, float* __restrict__ Mm,
                      float* __restrict__ bias2, float* __restrict__ Sl) {
  int b = blockIdx.x, o = threadIdx.x;
  if (b < 64) {
    int l = b;
    float tr = tcr[l], ti = tci[l];
    for (int i = 0; i < 64; ++i) {
      int idx = (l * 64 + i) * 64 + o;
      float r = wr[idx], s = wi[idx];
      A2[idx] = make_float2(cw[i * 64 + o] + tr * r - ti * s, tr * s + ti * r);
    }
  } else if (b < 128) {
    int j = b - 64;
    float wt = tv[o];
    float acc = 0.f;
    for (int i = 0; i < 64; ++i) acc = fmaf(c1w[j * 64 + i], sw[i * 64 + o], acc);
    Mm[j * 64 + o] = wt * acc;
    if (j == 0) {
      float bb = 0.f;
      for (int i = 0; i < 64; ++i) bb = fmaf(c1b[i], sw[i * 64 + o], bb);
      bias2[o] = wt * bb;
    }
  } else {
    int l = o;  // 64 threads
    float s = 0.f;
    for (int t = 0; t < 128; ++t) s += Deff[((size_t)t * 127 + 63) * 64 + l];
    Sl[l] = s;
  }
}

// ---------------- forward DFT as tiled GEMM ----------------
// grid (t=128, mh=2), block 256. out ftm[t][mm][c] float2. K=255 (p).
__global__ __launch_bounds__(256) void ct_dft(const float* __restrict__ x,
                                              const float2* __restrict__ T255,
                                              float2* __restrict__ ftm) {
  __shared__ float xs[64][64];    // [kp][c] 16 KB
  __shared__ float2 ts[64][64];   // [kp][mmIdx] 32 KB
  int t = blockIdx.x, mh = blockIdx.y;
  int tid = threadIdx.x;
  int cg = tid & 15, mg = tid >> 4;
  float accr[4][4], acci[4][4];
#pragma unroll
  for (int j = 0; j < 4; ++j)
#pragma unroll
    for (int q = 0; q < 4; ++q) { accr[j][q] = 0.f; acci[j][q] = 0.f; }
  for (int k0 = 0; k0 < 255; k0 += 64) {
    int kn = (255 - k0 < 64) ? 255 - k0 : 64;
    __syncthreads();
    {
      int r = tid >> 2, c4 = (tid & 3) * 16;
      if (r < kn) {
        const float4* src = (const float4*)(x + ((size_t)t * 255 + k0 + r) * 64 + c4);
        float4* dst = (float4*)&xs[r][c4];
        dst[0] = src[0]; dst[1] = src[1]; dst[2] = src[2]; dst[3] = src[3];
      }
    }
    for (int e = tid; e < 64 * 64; e += 256) {
      int r = e >> 6, mi = e & 63;
      if (r < kn) {
        int gcol = mh * 64 + mi; if (gcol > 126) gcol = 126;
        ts[r][mi] = T255[(size_t)(k0 + r) * 127 + gcol];
      }
    }
    __syncthreads();
#pragma unroll 4
    for (int k = 0; k < kn; ++k) {
      float4 xv = *(const float4*)&xs[k][cg * 4];
      float4 a01 = *(const float4*)&ts[k][mg * 4];
      float4 a23 = *(const float4*)&ts[k][mg * 4 + 2];
      float tr[4] = {a01.x, a01.z, a23.x, a23.z};
      float ti_[4] = {a01.y, a01.w, a23.y, a23.w};
      float xv4[4] = {xv.x, xv.y, xv.z, xv.w};
#pragma unroll
      for (int j = 0; j < 4; ++j)
#pragma unroll
        for (int q = 0; q < 4; ++q) {
          accr[j][q] = fmaf(xv4[q], tr[j], accr[j][q]);
          acci[j][q] = fmaf(xv4[q], ti_[j], acci[j][q]);
        }
    }
  }
#pragma unroll
  for (int j = 0; j < 4; ++j) {
    int gmm = mh * 64 + mg * 4 + j;
    if (gmm > 126) continue;
    float4* dst = (float4*)(ftm + ((size_t)t * 127 + gmm) * 64 + cg * 4);
    dst[0] = make_float4(accr[j][0], acci[j][0], accr[j][1], acci[j][1]);
    dst[1] = make_float4(accr[j][2], acci[j][2], accr[j][3], acci[j][3]);
  }
}

// ---------------- forward projection: flm[mm][l][c] = sum_t Deff[t][mm][l]*ftm[t][mm][c]
// grid (mm=127, lh=2), block 256. K=128 (t), 2 chunks.
__global__ __launch_bounds__(256) void ct_projf(const float* __restrict__ Deff,
                                                const float2* __restrict__ ftm,
                                                float2* __restrict__ flm) {
  __shared__ float Dsh[64][32];   // [t][lIdx] 8 KB
  __shared__ float2 fsh[64][64];  // [t][c] 32 KB
  int mm = blockIdx.x, lh = blockIdx.y;
  int tid = threadIdx.x;
  int cg = tid & 15, lg = tid >> 4;
  float accr[2][4], acci[2][4];
#pragma unroll
  for (int li = 0; li < 2; ++li)
#pragma unroll
    for (int q = 0; q < 4; ++q) { accr[li][q] = 0.f; acci[li][q] = 0.f; }
  for (int k0 = 0; k0 < 128; k0 += 64) {
    __syncthreads();
    for (int e = tid; e < 64 * 32; e += 256) {
      int r = e >> 5, li = e & 31;
      Dsh[r][li] = Deff[((size_t)(k0 + r) * 127 + mm) * 64 + lh * 32 + li];
    }
    for (int e = tid; e < 64 * 64; e += 256) {
      int r = e >> 6, c = e & 63;
      fsh[r][c] = ftm[((size_t)(k0 + r) * 127 + mm) * 64 + c];
    }
    __syncthreads();
#pragma unroll 4
    for (int k = 0; k < 64; ++k) {
      float4 f01 = *(const float4*)&fsh[k][cg * 4];
      float4 f23 = *(const float4*)&fsh[k][cg * 4 + 2];
      float2 d2 = *(const float2*)&Dsh[k][lg * 2];
      float fr[4] = {f01.x, f01.z, f23.x, f23.z};
      float fi[4] = {f01.y, f01.w, f23.y, f23.w};
      float dv[2] = {d2.x, d2.y};
#pragma unroll
      for (int li = 0; li < 2; ++li)
#pragma unroll
        for (int q = 0; q < 4; ++q) {
          accr[li][q] = fmaf(dv[li], fr[q], accr[li][q]);
          acci[li][q] = fmaf(dv[li], fi[q], acci[li][q]);
        }
    }
  }
#pragma unroll
  for (int li = 0; li < 2; ++li) {
    size_t row = (size_t)mm * 64 + lh * 32 + lg * 2 + li;
    float4* dst = (float4*)(flm + row * 64 + cg * 4);
    dst[0] = make_float4(accr[li][0], acci[li][0], accr[li][1], acci[li][1]);
    dst[1] = make_float4(accr[li][2], acci[li][2], accr[li][3], acci[li][3]);
  }
}

// ---------------- fused channel mixes: s = flm@A_l + scb ; h = flm@M (+bias spike)
// grid (l=64, mh=2, oh=2), block 256. K=64 (i), single chunk.
__global__ __launch_bounds__(256) void ct_mix(const float2* __restrict__ flm,
                                              const float2* __restrict__ A2,
                                              const float* __restrict__ Mm,
                                              const float* __restrict__ scb,
                                              const float* __restrict__ bias2,
                                              const float* __restrict__ Sl,
                                              float2* __restrict__ s2,
                                              float2* __restrict__ h2) {
  __shared__ float2 Ash[64][32];  // [i][oIdx] 16 KB
  __shared__ float Msh[64][32];   // 8 KB
  __shared__ float2 Bsh[64][66];  // [i][mmIdx] padded 33.8 KB
  int l = blockIdx.x, mh = blockIdx.y, oh = blockIdx.z;
  int tid = threadIdx.x;
  int og = tid & 15, mg = tid >> 4;
  for (int e = tid; e < 64 * 32; e += 256) {
    int r = e >> 5, oi = e & 31;
    Ash[r][oi] = A2[((size_t)l * 64 + r) * 64 + oh * 32 + oi];
    Msh[r][oi] = Mm[r * 64 + oh * 32 + oi];
  }
  for (int e = tid; e < 64 * 64; e += 256) {
    int mi = e >> 6, i = e & 63;
    int gmm = mh * 64 + mi; if (gmm > 126) gmm = 126;
    Bsh[i][mi] = flm[((size_t)gmm * 64 + l) * 64 + i];
  }
  __syncthreads();
  int o0 = oh * 32 + og * 2;
  float b0[2] = {scb[o0], scb[o0 + 1]};
  float sr[4][2], si[4][2], hr[4][2], hi[4][2];
#pragma unroll
  for (int jm = 0; jm < 4; ++jm)
#pragma unroll
    for (int qo = 0; qo < 2; ++qo) {
      sr[jm][qo] = b0[qo]; si[jm][qo] = 0.f; hr[jm][qo] = 0.f; hi[jm][qo] = 0.f;
    }
#pragma unroll 4
  for (int k = 0; k < 64; ++k) {
    float4 b01 = *(const float4*)&Bsh[k][mg * 4];
    float4 b23 = *(const float4*)&Bsh[k][mg * 4 + 2];
    float4 av = *(const float4*)&Ash[k][og * 2];
    float2 mv = *(const float2*)&Msh[k][og * 2];
    float br4[4] = {b01.x, b01.z, b23.x, b23.z};
    float bi4[4] = {b01.y, b01.w, b23.y, b23.w};
    float ar2[2] = {av.x, av.z}, ai2[2] = {av.y, av.w};
    float mv2[2] = {mv.x, mv.y};
#pragma unroll
    for (int jm = 0; jm < 4; ++jm)
#pragma unroll
      for (int qo = 0; qo < 2; ++qo) {
        sr[jm][qo] = fmaf(br4[jm], ar2[qo], sr[jm][qo]);
        sr[jm][qo] = fmaf(-bi4[jm], ai2[qo], sr[jm][qo]);
        si[jm][qo] = fmaf(br4[jm], ai2[qo], si[jm][qo]);
        si[jm][qo] = fmaf(bi4[jm], ar2[qo], si[jm][qo]);
        hr[jm][qo] = fmaf(br4[jm], mv2[qo], hr[jm][qo]);
        hi[jm][qo] = fmaf(bi4[jm], mv2[qo], hi[jm][qo]);
      }
  }
  float Slv = Sl[l];
  float bb[2] = {bias2[o0], bias2[o0 + 1]};
#pragma unroll
  for (int jm = 0; jm < 4; ++jm) {
    int gmm = mh * 64 + mg * 4 + jm;
    if (gmm > 126) continue;
    if (gmm == 63) {
#pragma unroll
      for (int qo = 0; qo < 2; ++qo)
        hr[jm][qo] = fmaf(255.0f * Slv, bb[qo], hr[jm][qo]);
    }
    size_t row = ((size_t)gmm * 64 + l) * 64 + o0;
    *(float4*)(s2 + row) = make_float4(sr[jm][0], si[jm][0], sr[jm][1], si[jm][1]);
    *(float4*)(h2 + row) = make_float4(hr[jm][0], hi[jm][0], hr[jm][1], hi[jm][1]);
  }
}

// ---------------- inverse projection: fo[t][mm][c] = sum_l Dinv[mm][l][t]*in[mm][l][c]
// grid (mm=127, br=2), block 256. K=64 (l), single chunk.
__global__ __launch_bounds__(256) void ct_proji(const float* __restrict__ Dinv,
                                                const float2* __restrict__ s2,
                                                const float2* __restrict__ h2,
                                                float2* __restrict__ fo_s,
                                                float2* __restrict__ fo_h) {
  __shared__ float Dsh[64][64];   // [l][t] 16 KB
  __shared__ float2 Bsh[64][64];  // [l][c] 32 KB
  int mm = blockIdx.x, br = blockIdx.y;
  const float2* in2 = br ? h2 : s2;
  float2* out2 = br ? fo_h : fo_s;
  int tid = threadIdx.x;
  int cg = tid & 15, tg = tid >> 4;
  for (int e = tid; e < 64 * 64; e += 256) {
    int r = e >> 6, c = e & 63;
    Dsh[r][c] = Dinv[((size_t)mm * 64 + r) * 64 + c];
    Bsh[r][c] = in2[((size_t)mm * 64 + r) * 64 + c];
  }
  __syncthreads();
  float accr[4][4], acci[4][4];
#pragma unroll
  for (int j = 0; j < 4; ++j)
#pragma unroll
    for (int q = 0; q < 4; ++q) { accr[j][q] = 0.f; acci[j][q] = 0.f; }
#pragma unroll 4
  for (int k = 0; k < 64; ++k) {
    float4 f01 = *(const float4*)&Bsh[k][cg * 4];
    float4 f23 = *(const float4*)&Bsh[k][cg * 4 + 2];
    float4 d4 = *(const float4*)&Dsh[k][tg * 4];
    float fr[4] = {f01.x, f01.z, f23.x, f23.z};
    float fi[4] = {f01.y, f01.w, f23.y, f23.w};
    float dv[4] = {d4.x, d4.y, d4.z, d4.w};
#pragma unroll
    for (int j = 0; j < 4; ++j)
#pragma unroll
      for (int q = 0; q < 4; ++q) {
        accr[j][q] = fmaf(dv[j], fr[q], accr[j][q]);
        acci[j][q] = fmaf(dv[j], fi[q], acci[j][q]);
      }
  }
#pragma unroll
  for (int j = 0; j < 4; ++j) {
    int t = tg * 4 + j;
    float4* dst = (float4*)(out2 + ((size_t)t * 127 + mm) * 64 + cg * 4);
    dst[0] = make_float4(accr[j][0], acci[j][0], accr[j][1], acci[j][1]);
    dst[1] = make_float4(accr[j][2], acci[j][2], accr[j][3], acci[j][3]);
  }
}

// ---------------- inverse DFT as tiled GEMM (real output) ----------------
// grid (t=64, br=2, ph=2), block 256. K=127 (mm) in 4 chunks of 32.
__global__ __launch_bounds__(256) void ct_idft(const float2* __restrict__ T127,
                                               const float2* __restrict__ fo_s,
                                               const float2* __restrict__ fo_h,
                                               float* __restrict__ xsb,
                                               float* __restrict__ hsb) {
  __shared__ float2 Ash[32][64];  // [k][pIdx] 16 KB
  __shared__ float2 Bsh[32][64];  // [k][c] 16 KB
  int t = blockIdx.x, br = blockIdx.y, ph = blockIdx.z;
  const float2* fo = br ? fo_h : fo_s;
  float* outp = br ? hsb : xsb;
  int tid = threadIdx.x;
  int cg = tid & 15, pg = tid >> 4;
  float acc[4][4];
#pragma unroll
  for (int j = 0; j < 4; ++j)
#pragma unroll
    for (int q = 0; q < 4; ++q) acc[j][q] = 0.f;
  for (int k0 = 0; k0 < 127; k0 += 32) {
    int kn = (127 - k0 < 32) ? 127 - k0 : 32;
    __syncthreads();
    for (int e = tid; e < 32 * 64; e += 256) {
      int r = e >> 6, pi = e & 63;
      if (r < kn) {
        int gp = ph * 64 + pi; if (gp > 126) gp = 126;
        Ash[r][pi] = T127[(size_t)(k0 + r) * 127 + gp];
      }
    }
    for (int e = tid; e < 32 * 64; e += 256) {
      int r = e >> 6, c = e & 63;
      if (r < kn) Bsh[r][c] = fo[((size_t)t * 127 + k0 + r) * 64 + c];
    }
    __syncthreads();
#pragma unroll 4
    for (int k = 0; k < kn; ++k) {
      float4 f01 = *(const float4*)&Bsh[k][cg * 4];
      float4 f23 = *(const float4*)&Bsh[k][cg * 4 + 2];
      float4 a01 = *(const float4*)&Ash[k][pg * 4];
      float4 a23 = *(const float4*)&Ash[k][pg * 4 + 2];
      float fr[4] = {f01.x, f01.z, f23.x, f23.z};
      float fi[4] = {f01.y, f01.w, f23.y, f23.w};
      float wc[4] = {a01.x, a01.z, a23.x, a23.z};
      float ws[4] = {a01.y, a01.w, a23.y, a23.w};
#pragma unroll
      for (int j = 0; j < 4; ++j)
#pragma unroll
        for (int q = 0; q < 4; ++q) {
          acc[j][q] = fmaf(fr[q], wc[j], acc[j][q]);
          acc[j][q] = fmaf(fi[q], -ws[j], acc[j][q]);
        }
    }
  }
#pragma unroll
  for (int j = 0; j < 4; ++j) {
    int gp = ph * 64 + pg * 4 + j;
    if (gp > 126) continue;
    *(float4*)(outp + ((size_t)t * 127 + gp) * 64 + cg * 4) =
        make_float4(acc[j][0], acc[j][1], acc[j][2], acc[j][3]);
  }
}

// ---------------- epilogue ----------------
__global__ void ct_final(const float* __restrict__ xs, const float* __restrict__ hs,
                         const float* __restrict__ c2w, const float* __restrict__ c2b,
                         const float* __restrict__ tv, const float* __restrict__ lns,
                         const float* __restrict__ lnb, float* __restrict__ out) {
  int bid = blockIdx.x;  // t*127+p
  int c = threadIdx.x;
  const float* hr = hs + (size_t)bid * 64;
  float acc = c2b[c] + tv[64 + c];
#pragma unroll 4
  for (int i = 0; i < 64; ++i) acc = fmaf(hr[i], c2w[i * 64 + c], acc);
  float xv = xs[(size_t)bid * 64 + c];
  float ss = wave_sum64(xv * xv);
  xv = xv / (sqrtf(ss) + 1e-6f);
  float y = xv + acc;
  float g = gelu_tanh(y);
  float mu = wave_sum64(g) * (1.0f / 64.0f);
  float d = g - mu;
  float var = wave_sum64(d * d) * (1.0f / 64.0f);
  out[(size_t)bid * 64 + c] = d * rsqrtf(var + 1e-6f) * lns[c] + lnb[c];
}

// ---------------- host launcher ----------------
extern "C" void kernel_launch(void* const* d_in, const int* in_sizes, int n_in,
                              void* d_out, int out_size, void* d_ws, size_t ws_size,
                              hipStream_t stream) {
  const float* x = (const float*)d_in[0];
  const float* temb = (const float*)d_in[1];
  const float* scw = (const float*)d_in[2];
  const float* scb = (const float*)d_in[3];
  const float* swr = (const float*)d_in[4];
  const float* swi = (const float*)d_in[5];
  const float* strw = (const float*)d_in[6];
  const float* strb = (const float*)d_in[7];
  const float* stiw = (const float*)d_in[8];
  const float* stib = (const float*)d_in[9];
  const float* c1w = (const float*)d_in[10];
  const float* c1b = (const float*)d_in[11];
  const float* stw = (const float*)d_in[12];
  const float* stb = (const float*)d_in[13];
  const float* sweight = (const float*)d_in[14];
  const float* c2w = (const float*)d_in[15];
  const float* c2b = (const float*)d_in[16];
  const float* lns = (const float*)d_in[17];
  const float* lnb = (const float*)d_in[18];
  float* out = (float*)d_out;

  char* base = (char*)d_ws;
  size_t off = 0;
  auto alloc = [&](size_t bytes) -> void* {
    void* p = base + off;
    off += (bytes + 255) & ~(size_t)255;
    return p;
  };
  float* tcr = (float*)alloc(64 * sizeof(float));
  float* tci = (float*)alloc(64 * sizeof(float));
  float* tv = (float*)alloc(128 * sizeof(float));
  float* Mm = (float*)alloc(4096 * sizeof(float));
  float* bias2 = (float*)alloc(64 * sizeof(float));
  float* Sl = (float*)alloc(64 * sizeof(float));
  float2* A2 = (float2*)alloc(262144 * sizeof(float2));
  float* Deff = (float*)alloc(1040384 * sizeof(float));   // [t<128][mm][l]
  float* Dinv = (float*)alloc(520192 * sizeof(float));    // [mm][l][t<64]
  float2* T255 = (float2*)alloc(32385 * sizeof(float2));  // [p][mm]
  float2* T127 = (float2*)alloc(16129 * sizeof(float2));  // [mm][p]
  float2* ftm = (float2*)alloc(1040384 * sizeof(float2)); // [t<128][mm][c]
  float2* flm = (float2*)alloc(520192 * sizeof(float2));  // [mm][l][c]
  if (off > ws_size) return;  // workspace too small -> visible failure
  // aliases with disjoint lifetimes:
  float2* s2 = ftm;                    // after projf consumed ftm
  float2* h2 = ftm + 520192;
  float2* fo_s = (float2*)Deff;        // after projf/AM consumed Deff (4.16 MB)
  float2* fo_h = flm;                  // after mix consumed flm
  float* xsb = (float*)ftm;            // after proji consumed s2/h2
  float* hsb = (float*)ftm + 520192;

  hipLaunchKernelGGL(ct_prep, dim3(1), dim3(192), 0, stream, temb, strw, strb, stiw, stib,
                     stw, stb, tcr, tci, tv);
  hipLaunchKernelGGL(ct_wigner, dim3(255), dim3(128), 0, stream, Deff, Dinv);
  hipLaunchKernelGGL(ct_tw2, dim3(127), dim3(256), 0, stream, T255, T127);
  hipLaunchKernelGGL(ct_AM, dim3(129), dim3(64), 0, stream, scw, swr, swi, tcr, tci,
                     c1w, c1b, sweight, tv, Deff, A2, Mm, bias2, Sl);
  hipLaunchKernelGGL(ct_dft, dim3(128, 2), dim3(256), 0, stream, x, T255, ftm);
  hipLaunchKernelGGL(ct_projf, dim3(127, 2), dim3(256), 0, stream, Deff, ftm, flm);
  hipLaunchKernelGGL(ct_mix, dim3(64, 2, 2), dim3(256), 0, stream, flm, A2, Mm,
                     scb, bias2, Sl, s2, h2);
  hipLaunchKernelGGL(ct_proji, dim3(127, 2), dim3(256), 0, stream, Dinv, s2, h2, fo_s, fo_h);
  hipLaunchKernelGGL(ct_idft, dim3(64, 2, 2), dim3(256), 0, stream, T127, fo_s, fo_h,
                     xsb, hsb);
  hipLaunchKernelGGL(ct_final, dim3(8128), dim3(64), 0, stream, xsb, hsb, c2w, c2b, tv,
                     lns, lnb, out);
}

// Round 6
// 251.622 us; speedup vs baseline: 2.1552x; 1.0929x over previous
//
#include <hip/hip_runtime.h>
#include <math.h>

#define DPI 3.141592653589793238462643383279502884

// ---------------- device helpers ----------------
__device__ __forceinline__ float wave_sum64(float v) {
#pragma unroll
  for (int off = 32; off > 0; off >>= 1) v += __shfl_xor(v, off, 64);
  return v;
}

__device__ __forceinline__ float gelu_tanh(float v) {
  float u = 0.7978845608028654f * (v + 0.044715f * v * v * v);
  return 0.5f * v * (1.0f + tanhf(u));
}

// ---------------- setup: Wigner tables + twiddles + t-emb projections ----------------
// blocks 0..127   : Deff[t][mm][l] (t=b, lanes=mm; quad-weight sum lane-parallel)
// blocks 128..254 : Dinv[mm][l][t] (mm=b-128, lanes=t)
// blocks 255..444 : twiddle tables T255, T127
// block  445      : t-embedding projections (tcr/tci/tv)
__global__ __launch_bounds__(256) void ct_setup(
    float* __restrict__ Deff, float* __restrict__ Dinv,
    float2* __restrict__ T255, float2* __restrict__ T127,
    const float* __restrict__ temb, const float* __restrict__ trw,
    const float* __restrict__ trb, const float* __restrict__ tiw,
    const float* __restrict__ tib, const float* __restrict__ stw,
    const float* __restrict__ stb, float* tcr, float* tci, float* tv) {
  int b = blockIdx.x;
  int tid = threadIdx.x;
  if (b >= 255) {
    if (b == 445) {  // prep
      if (tid < 64) {
        float ar = trb[tid], ai = tib[tid];
        for (int k = 0; k < 256; ++k) {
          float e = temb[k];
          ar = fmaf(e, trw[k * 64 + tid], ar);
          ai = fmaf(e, tiw[k * 64 + tid], ai);
        }
        tcr[tid] = ar; tci[tid] = ai;
      } else if (tid < 192) {
        int j = tid - 64;
        float a = stb[j];
        for (int k = 0; k < 256; ++k) a = fmaf(temb[k], stw[k * 128 + j], a);
        tv[j] = a;
      }
    } else {  // twiddles
      int id = (b - 255) * 256 + tid;
      if (id < 255 * 127) {
        int p = id / 127, mm = id % 127;
        double ang = 2.0 * DPI * (double)((mm - 63) * p) / 255.0;
        T255[id] = make_float2((float)cos(ang), (float)(-sin(ang)));
      }
      if (id < 127 * 127) {
        int mm = id / 127, p = id % 127;
        double ang = 2.0 * DPI * (double)((mm - 63) * p) / 127.0;
        T127[id] = make_float2((float)cos(ang), (float)sin(ang));
      }
    }
    return;
  }
  // ---- wigner ----
  __shared__ double red[64];
  __shared__ float clf[64];
  int mode = (b < 128) ? 0 : 1;
  if (tid < 64)
    clf[tid] = (float)(-sqrt((2.0 * tid + 1.0) / (4.0 * DPI)));
  int t, mm;
  if (mode == 0) { t = b; mm = tid; }
  else { mm = b - 128; t = tid; }
  double denomN = (mode == 0) ? 255.0 : 127.0;
  double beta = (2.0 * t + 1.0) * DPI / denomN;
  float coeff;
  if (mode == 0) {
    // quad-weight pair sum, lane-parallel: (4 + sum 8 cos(k*beta)/(1-k^2))/255
    if (tid < 63) {
      int k = 2 * (tid + 1);
      red[tid] = 8.0 * cos((double)k * beta) / (1.0 - (double)k * (double)k);
    } else if (tid == 63) {
      red[63] = 4.0;
    }
    __syncthreads();
    for (int s = 32; s > 0; s >>= 1) {
      if (tid < s) red[tid] += red[tid + s];
      __syncthreads();
    }
    double s = red[0] / 255.0;
    if (t == 127) s *= 0.5;
    coeff = (float)(s * (2.0 * DPI / 255.0));
    if (tid >= 127) return;
  } else {
    __syncthreads();  // keep barrier count uniform enough (block-uniform path)
    coeff = 1.0f;
    if (tid >= 64) return;
  }
  int m = mm - 63;
  double cb = cos(beta);
  double ch = cos(0.5 * beta), sh = sin(0.5 * beta);
  int am = (m < 0) ? -m : m;
  int l0v = (am > 1) ? am : 1;
  double seed;
  if (m >= 1) {
    double j = (double)m;
    double K = exp(0.5 * (lgamma(2.0 * j + 1.0) - lgamma(j) - lgamma(j + 2.0)));
    double sgn = ((m + 1) & 1) ? -1.0 : 1.0;
    seed = sgn * K * pow(ch, j - 1.0) * pow(sh, j + 1.0);
  } else if (m <= -1) {
    double j = (double)(-m);
    double K = exp(0.5 * (lgamma(2.0 * j + 1.0) - lgamma(j) - lgamma(j + 2.0)));
    seed = K * pow(ch, j + 1.0) * pow(sh, j - 1.0);
  } else {
    seed = -sqrt(2.0) * sh * ch;
  }
  // fp32 upward recurrence (dominant-solution direction -> stable; underflowed
  // seeds correspond to true values < 1e-28 after growth -> negligible).
  float dl = (float)seed, dm1 = 0.0f, S_cur = 0.0f;
  float cbf = (float)cb, mf = (float)m;
  for (int l = 0; l < 64; ++l) {
    float val = 0.0f;
    if (l >= l0v) {
      val = dl * coeff * clf[l];
      float Ld = (float)l, lp = Ld + 1.0f;
      float S_next = sqrtf((lp * lp - mf * mf) * (lp * lp - 1.0f));
      float num1 = (2.0f * Ld + 1.0f) * (Ld * lp * cbf + mf);
      float dn = (num1 * dl - lp * S_cur * dm1) / (Ld * S_next);
      dm1 = dl; dl = dn; S_cur = S_next;
    }
    if (mode == 0) Deff[((size_t)t * 127 + mm) * 64 + l] = val;
    else Dinv[((size_t)mm * 64 + l) * 64 + t] = val;
  }
}

// A2[l][i][o]; M[j][o]; bias2[o]; Sl[l] = sum_t Deff[t][63][l]
__global__ void ct_AM(const float* __restrict__ cw, const float* __restrict__ wr,
                      const float* __restrict__ wi, const float* __restrict__ tcr,
                      const float* __restrict__ tci, const float* __restrict__ c1w,
                      const float* __restrict__ c1b, const float* __restrict__ sw,
                      const float* __restrict__ tv, const float* __restrict__ Deff,
                      float2* __restrict__ A2, float* __restrict__ Mm,
                      float* __restrict__ bias2, float* __restrict__ Sl) {
  int b = blockIdx.x, o = threadIdx.x;
  if (b < 64) {
    int l = b;
    float tr = tcr[l], ti = tci[l];
    for (int i = 0; i < 64; ++i) {
      int idx = (l * 64 + i) * 64 + o;
      float r = wr[idx], s = wi[idx];
      A2[idx] = make_float2(cw[i * 64 + o] + tr * r - ti * s, tr * s + ti * r);
    }
  } else if (b < 128) {
    int j = b - 64;
    float wt = tv[o];
    float acc = 0.f;
    for (int i = 0; i < 64; ++i) acc = fmaf(c1w[j * 64 + i], sw[i * 64 + o], acc);
    Mm[j * 64 + o] = wt * acc;
    if (j == 0) {
      float bb = 0.f;
      for (int i = 0; i < 64; ++i) bb = fmaf(c1b[i], sw[i * 64 + o], bb);
      bias2[o] = wt * bb;
    }
  } else {
    int l = o;
    float s = 0.f;
    for (int t = 0; t < 128; ++t) s += Deff[((size_t)t * 127 + 63) * 64 + l];
    Sl[l] = s;
  }
}

// ---------------- forward DFT as tiled GEMM, K split over ph ----------------
// grid (t=128, mh=2, ph=2), block 256. ph=0: p 0..127 -> ftmA; ph=1: p 128..254 -> ftmB.
__global__ __launch_bounds__(256) void ct_dft(const float* __restrict__ x,
                                              const float2* __restrict__ T255,
                                              float2* __restrict__ ftmA,
                                              float2* __restrict__ ftmB) {
  __shared__ float xs_[64][64];   // [kp][c] 16 KB
  __shared__ float2 ts[64][64];   // [kp][mmIdx] 32 KB
  int t = blockIdx.x, mh = blockIdx.y, ph = blockIdx.z;
  float2* ftm = ph ? ftmB : ftmA;
  int pbase = ph * 128;
  int Ktot = ph ? 127 : 128;
  int tid = threadIdx.x;
  int cg = tid & 15, mg = tid >> 4;
  float accr[4][4], acci[4][4];
#pragma unroll
  for (int j = 0; j < 4; ++j)
#pragma unroll
    for (int q = 0; q < 4; ++q) { accr[j][q] = 0.f; acci[j][q] = 0.f; }
  for (int k0 = 0; k0 < Ktot; k0 += 64) {
    int kn = (Ktot - k0 < 64) ? Ktot - k0 : 64;
    __syncthreads();
    {
      int r = tid >> 2, c4 = (tid & 3) * 16;
      if (r < kn) {
        const float4* src = (const float4*)(x + ((size_t)t * 255 + pbase + k0 + r) * 64 + c4);
        float4* dst = (float4*)&xs_[r][c4];
        dst[0] = src[0]; dst[1] = src[1]; dst[2] = src[2]; dst[3] = src[3];
      }
    }
    for (int e = tid; e < 64 * 64; e += 256) {
      int r = e >> 6, mi = e & 63;
      if (r < kn) {
        int gcol = mh * 64 + mi; if (gcol > 126) gcol = 126;
        ts[r][mi] = T255[(size_t)(pbase + k0 + r) * 127 + gcol];
      }
    }
    __syncthreads();
#pragma unroll 4
    for (int k = 0; k < kn; ++k) {
      float4 xv = *(const float4*)&xs_[k][cg * 4];
      float4 a01 = *(const float4*)&ts[k][mg * 4];
      float4 a23 = *(const float4*)&ts[k][mg * 4 + 2];
      float tr[4] = {a01.x, a01.z, a23.x, a23.z};
      float ti_[4] = {a01.y, a01.w, a23.y, a23.w};
      float xv4[4] = {xv.x, xv.y, xv.z, xv.w};
#pragma unroll
      for (int j = 0; j < 4; ++j)
#pragma unroll
        for (int q = 0; q < 4; ++q) {
          accr[j][q] = fmaf(xv4[q], tr[j], accr[j][q]);
          acci[j][q] = fmaf(xv4[q], ti_[j], acci[j][q]);
        }
    }
  }
#pragma unroll
  for (int j = 0; j < 4; ++j) {
    int gmm = mh * 64 + mg * 4 + j;
    if (gmm > 126) continue;
    float4* dst = (float4*)(ftm + ((size_t)t * 127 + gmm) * 64 + cg * 4);
    dst[0] = make_float4(accr[j][0], acci[j][0], accr[j][1], acci[j][1]);
    dst[1] = make_float4(accr[j][2], acci[j][2], accr[j][3], acci[j][3]);
  }
}

// ---------------- forward projection: flm[mm][l][c] = sum_t Deff[t][mm][l]*(ftmA+ftmB)
// grid (mm=127, lh=2), block 256.
__global__ __launch_bounds__(256) void ct_projf(const float* __restrict__ Deff,
                                                const float2* __restrict__ ftmA,
                                                const float2* __restrict__ ftmB,
                                                float2* __restrict__ flm) {
  __shared__ float Dsh[64][32];   // [t][lIdx] 8 KB
  __shared__ float2 fsh[64][64];  // [t][c] 32 KB
  int mm = blockIdx.x, lh = blockIdx.y;
  int tid = threadIdx.x;
  int cg = tid & 15, lg = tid >> 4;
  float accr[2][4], acci[2][4];
#pragma unroll
  for (int li = 0; li < 2; ++li)
#pragma unroll
    for (int q = 0; q < 4; ++q) { accr[li][q] = 0.f; acci[li][q] = 0.f; }
  for (int k0 = 0; k0 < 128; k0 += 64) {
    __syncthreads();
    for (int e = tid; e < 64 * 32; e += 256) {
      int r = e >> 5, li = e & 31;
      Dsh[r][li] = Deff[((size_t)(k0 + r) * 127 + mm) * 64 + lh * 32 + li];
    }
    for (int e = tid; e < 64 * 64; e += 256) {
      int r = e >> 6, c = e & 63;
      size_t idx = ((size_t)(k0 + r) * 127 + mm) * 64 + c;
      float2 a = ftmA[idx], b2 = ftmB[idx];
      fsh[r][c] = make_float2(a.x + b2.x, a.y + b2.y);
    }
    __syncthreads();
#pragma unroll 4
    for (int k = 0; k < 64; ++k) {
      float4 f01 = *(const float4*)&fsh[k][cg * 4];
      float4 f23 = *(const float4*)&fsh[k][cg * 4 + 2];
      float2 d2 = *(const float2*)&Dsh[k][lg * 2];
      float fr[4] = {f01.x, f01.z, f23.x, f23.z};
      float fi[4] = {f01.y, f01.w, f23.y, f23.w};
      float dv[2] = {d2.x, d2.y};
#pragma unroll
      for (int li = 0; li < 2; ++li)
#pragma unroll
        for (int q = 0; q < 4; ++q) {
          accr[li][q] = fmaf(dv[li], fr[q], accr[li][q]);
          acci[li][q] = fmaf(dv[li], fi[q], acci[li][q]);
        }
    }
  }
#pragma unroll
  for (int li = 0; li < 2; ++li) {
    size_t row = (size_t)mm * 64 + lh * 32 + lg * 2 + li;
    float4* dst = (float4*)(flm + row * 64 + cg * 4);
    dst[0] = make_float4(accr[li][0], acci[li][0], accr[li][1], acci[li][1]);
    dst[1] = make_float4(accr[li][2], acci[li][2], accr[li][3], acci[li][3]);
  }
}

// ---------------- fused channel mixes: s = flm@A_l + scb ; h = flm@M (+bias spike)
// grid (l=64, mh=2, oh=2), block 256.
__global__ __launch_bounds__(256) void ct_mix(const float2* __restrict__ flm,
                                              const float2* __restrict__ A2,
                                              const float* __restrict__ Mm,
                                              const float* __restrict__ scb,
                                              const float* __restrict__ bias2,
                                              const float* __restrict__ Sl,
                                              float2* __restrict__ s2,
                                              float2* __restrict__ h2) {
  __shared__ float2 Ash[64][32];
  __shared__ float Msh[64][32];
  __shared__ float2 Bsh[64][66];
  int l = blockIdx.x, mh = blockIdx.y, oh = blockIdx.z;
  int tid = threadIdx.x;
  int og = tid & 15, mg = tid >> 4;
  for (int e = tid; e < 64 * 32; e += 256) {
    int r = e >> 5, oi = e & 31;
    Ash[r][oi] = A2[((size_t)l * 64 + r) * 64 + oh * 32 + oi];
    Msh[r][oi] = Mm[r * 64 + oh * 32 + oi];
  }
  for (int e = tid; e < 64 * 64; e += 256) {
    int mi = e >> 6, i = e & 63;
    int gmm = mh * 64 + mi; if (gmm > 126) gmm = 126;
    Bsh[i][mi] = flm[((size_t)gmm * 64 + l) * 64 + i];
  }
  __syncthreads();
  int o0 = oh * 32 + og * 2;
  float b0[2] = {scb[o0], scb[o0 + 1]};
  float sr[4][2], si[4][2], hr[4][2], hi[4][2];
#pragma unroll
  for (int jm = 0; jm < 4; ++jm)
#pragma unroll
    for (int qo = 0; qo < 2; ++qo) {
      sr[jm][qo] = b0[qo]; si[jm][qo] = 0.f; hr[jm][qo] = 0.f; hi[jm][qo] = 0.f;
    }
#pragma unroll 4
  for (int k = 0; k < 64; ++k) {
    float4 b01 = *(const float4*)&Bsh[k][mg * 4];
    float4 b23 = *(const float4*)&Bsh[k][mg * 4 + 2];
    float4 av = *(const float4*)&Ash[k][og * 2];
    float2 mv = *(const float2*)&Msh[k][og * 2];
    float br4[4] = {b01.x, b01.z, b23.x, b23.z};
    float bi4[4] = {b01.y, b01.w, b23.y, b23.w};
    float ar2[2] = {av.x, av.z}, ai2[2] = {av.y, av.w};
    float mv2[2] = {mv.x, mv.y};
#pragma unroll
    for (int jm = 0; jm < 4; ++jm)
#pragma unroll
      for (int qo = 0; qo < 2; ++qo) {
        sr[jm][qo] = fmaf(br4[jm], ar2[qo], sr[jm][qo]);
        sr[jm][qo] = fmaf(-bi4[jm], ai2[qo], sr[jm][qo]);
        si[jm][qo] = fmaf(br4[jm], ai2[qo], si[jm][qo]);
        si[jm][qo] = fmaf(bi4[jm], ar2[qo], si[jm][qo]);
        hr[jm][qo] = fmaf(br4[jm], mv2[qo], hr[jm][qo]);
        hi[jm][qo] = fmaf(bi4[jm], mv2[qo], hi[jm][qo]);
      }
  }
  float Slv = Sl[l];
  float bb[2] = {bias2[o0], bias2[o0 + 1]};
#pragma unroll
  for (int jm = 0; jm < 4; ++jm) {
    int gmm = mh * 64 + mg * 4 + jm;
    if (gmm > 126) continue;
    if (gmm == 63) {
#pragma unroll
      for (int qo = 0; qo < 2; ++qo)
        hr[jm][qo] = fmaf(255.0f * Slv, bb[qo], hr[jm][qo]);
    }
    size_t row = ((size_t)gmm * 64 + l) * 64 + o0;
    *(float4*)(s2 + row) = make_float4(sr[jm][0], si[jm][0], sr[jm][1], si[jm][1]);
    *(float4*)(h2 + row) = make_float4(hr[jm][0], hi[jm][0], hr[jm][1], hi[jm][1]);
  }
}

// ---------------- inverse projection ----------------
// grid (mm=127, br=2), block 256. fo[t][mm][c] = sum_l Dinv[mm][l][t]*in[mm][l][c]
__global__ __launch_bounds__(256) void ct_proji(const float* __restrict__ Dinv,
                                                const float2* __restrict__ s2,
                                                const float2* __restrict__ h2,
                                                float2* __restrict__ fo_s,
                                                float2* __restrict__ fo_h) {
  __shared__ float Dsh[64][64];
  __shared__ float2 Bsh[64][64];
  int mm = blockIdx.x, br = blockIdx.y;
  const float2* in2 = br ? h2 : s2;
  float2* out2 = br ? fo_h : fo_s;
  int tid = threadIdx.x;
  int cg = tid & 15, tg = tid >> 4;
  for (int e = tid; e < 64 * 64; e += 256) {
    int r = e >> 6, c = e & 63;
    Dsh[r][c] = Dinv[((size_t)mm * 64 + r) * 64 + c];
    Bsh[r][c] = in2[((size_t)mm * 64 + r) * 64 + c];
  }
  __syncthreads();
  float accr[4][4], acci[4][4];
#pragma unroll
  for (int j = 0; j < 4; ++j)
#pragma unroll
    for (int q = 0; q < 4; ++q) { accr[j][q] = 0.f; acci[j][q] = 0.f; }
#pragma unroll 4
  for (int k = 0; k < 64; ++k) {
    float4 f01 = *(const float4*)&Bsh[k][cg * 4];
    float4 f23 = *(const float4*)&Bsh[k][cg * 4 + 2];
    float4 d4 = *(const float4*)&Dsh[k][tg * 4];
    float fr[4] = {f01.x, f01.z, f23.x, f23.z};
    float fi[4] = {f01.y, f01.w, f23.y, f23.w};
    float dv[4] = {d4.x, d4.y, d4.z, d4.w};
#pragma unroll
    for (int j = 0; j < 4; ++j)
#pragma unroll
      for (int q = 0; q < 4; ++q) {
        accr[j][q] = fmaf(dv[j], fr[q], accr[j][q]);
        acci[j][q] = fmaf(dv[j], fi[q], acci[j][q]);
      }
  }
#pragma unroll
  for (int j = 0; j < 4; ++j) {
    int t = tg * 4 + j;
    float4* dst = (float4*)(out2 + ((size_t)t * 127 + mm) * 64 + cg * 4);
    dst[0] = make_float4(accr[j][0], acci[j][0], accr[j][1], acci[j][1]);
    dst[1] = make_float4(accr[j][2], acci[j][2], accr[j][3], acci[j][3]);
  }
}

// ---------------- fused inverse DFT (both branches) + epilogue ----------------
// grid (t=64, ph=2), block 256. Computes xs,hs [64p][64c] tiles in regs,
// then conv2 + norm + residual + gelu + layernorm in-block.
__global__ __launch_bounds__(256) void ct_idft_final(
    const float2* __restrict__ T127, const float2* __restrict__ fo_s,
    const float2* __restrict__ fo_h, const float* __restrict__ c2w,
    const float* __restrict__ c2b, const float* __restrict__ tv,
    const float* __restrict__ lns, const float* __restrict__ lnb,
    float* __restrict__ out) {
  __shared__ float sm[12288];  // 48 KB, phase-reused
  float2(*Ash)[64] = (float2(*)[64])sm;            // [32][64] T127 tile
  float2(*Bs)[64] = (float2(*)[64])(sm + 4096);    // [32][64] fo_s tile
  float2(*Bh)[64] = (float2(*)[64])(sm + 8192);    // [32][64] fo_h tile
  int t = blockIdx.x, ph = blockIdx.y;
  int tid = threadIdx.x;
  int cg = tid & 15, pg = tid >> 4;
  float as[4][4], ah[4][4];
#pragma unroll
  for (int j = 0; j < 4; ++j)
#pragma unroll
    for (int q = 0; q < 4; ++q) { as[j][q] = 0.f; ah[j][q] = 0.f; }
  for (int k0 = 0; k0 < 127; k0 += 32) {
    int kn = (127 - k0 < 32) ? 127 - k0 : 32;
    __syncthreads();
    for (int e = tid; e < 32 * 64; e += 256) {
      int r = e >> 6, pi = e & 63;
      if (r < kn) {
        int gp = ph * 64 + pi; if (gp > 126) gp = 126;
        Ash[r][pi] = T127[(size_t)(k0 + r) * 127 + gp];
      }
    }
    for (int e = tid; e < 32 * 64; e += 256) {
      int r = e >> 6, c = e & 63;
      if (r < kn) {
        size_t idx = ((size_t)t * 127 + k0 + r) * 64 + c;
        Bs[r][c] = fo_s[idx];
        Bh[r][c] = fo_h[idx];
      }
    }
    __syncthreads();
#pragma unroll 4
    for (int k = 0; k < kn; ++k) {
      float4 s01 = *(const float4*)&Bs[k][cg * 4];
      float4 s23 = *(const float4*)&Bs[k][cg * 4 + 2];
      float4 h01 = *(const float4*)&Bh[k][cg * 4];
      float4 h23 = *(const float4*)&Bh[k][cg * 4 + 2];
      float4 a01 = *(const float4*)&Ash[k][pg * 4];
      float4 a23 = *(const float4*)&Ash[k][pg * 4 + 2];
      float srf[4] = {s01.x, s01.z, s23.x, s23.z};
      float sif[4] = {s01.y, s01.w, s23.y, s23.w};
      float hrf[4] = {h01.x, h01.z, h23.x, h23.z};
      float hif[4] = {h01.y, h01.w, h23.y, h23.w};
      float wc[4] = {a01.x, a01.z, a23.x, a23.z};
      float ws[4] = {a01.y, a01.w, a23.y, a23.w};
#pragma unroll
      for (int j = 0; j < 4; ++j)
#pragma unroll
        for (int q = 0; q < 4; ++q) {
          as[j][q] = fmaf(srf[q], wc[j], as[j][q]);
          as[j][q] = fmaf(sif[q], -ws[j], as[j][q]);
          ah[j][q] = fmaf(hrf[q], wc[j], ah[j][q]);
          ah[j][q] = fmaf(hif[q], -ws[j], ah[j][q]);
        }
    }
  }
  __syncthreads();
  // phase 2: epilogue. reuse sm: xs_t [64][64], hs_t [64][64], c2w [64][64]
  float* xs_t = sm;
  float* hs_t = sm + 4096;
  float* wsh = sm + 8192;
#pragma unroll
  for (int j = 0; j < 4; ++j) {
    int p = pg * 4 + j;
#pragma unroll
    for (int q = 0; q < 4; ++q) {
      xs_t[p * 64 + cg * 4 + q] = as[j][q];
      hs_t[p * 64 + cg * 4 + q] = ah[j][q];
    }
  }
  for (int e = tid; e < 1024; e += 256) ((float4*)wsh)[e] = ((const float4*)c2w)[e];
  __syncthreads();
  int lane = tid & 63, w = tid >> 6;
  float cbv = c2b[lane] + tv[64 + lane];
  float lnsv = lns[lane], lnbv = lnb[lane];
  for (int pr = w; pr < 64; pr += 4) {
    int gp = ph * 64 + pr;
    if (gp > 126) continue;
    float acc = cbv;
#pragma unroll 4
    for (int i = 0; i < 64; ++i) acc = fmaf(hs_t[pr * 64 + i], wsh[i * 64 + lane], acc);
    float xv = xs_t[pr * 64 + lane];
    float ss = wave_sum64(xv * xv);
    xv = xv / (sqrtf(ss) + 1e-6f);
    float y = xv + acc;
    float g = gelu_tanh(y);
    float mu = wave_sum64(g) * (1.0f / 64.0f);
    float d = g - mu;
    float var = wave_sum64(d * d) * (1.0f / 64.0f);
    out[((size_t)t * 127 + gp) * 64 + lane] = d * rsqrtf(var + 1e-6f) * lnsv + lnbv;
  }
}

// ---------------- host launcher ----------------
extern "C" void kernel_launch(void* const* d_in, const int* in_sizes, int n_in,
                              void* d_out, int out_size, void* d_ws, size_t ws_size,
                              hipStream_t stream) {
  const float* x = (const float*)d_in[0];
  const float* temb = (const float*)d_in[1];
  const float* scw = (const float*)d_in[2];
  const float* scb = (const float*)d_in[3];
  const float* swr = (const float*)d_in[4];
  const float* swi = (const float*)d_in[5];
  const float* strw = (const float*)d_in[6];
  const float* strb = (const float*)d_in[7];
  const float* stiw = (const float*)d_in[8];
  const float* stib = (const float*)d_in[9];
  const float* c1w = (const float*)d_in[10];
  const float* c1b = (const float*)d_in[11];
  const float* stw = (const float*)d_in[12];
  const float* stb = (const float*)d_in[13];
  const float* sweight = (const float*)d_in[14];
  const float* c2w = (const float*)d_in[15];
  const float* c2b = (const float*)d_in[16];
  const float* lns = (const float*)d_in[17];
  const float* lnb = (const float*)d_in[18];
  float* out = (float*)d_out;

  char* base = (char*)d_ws;
  size_t off = 0;
  auto alloc = [&](size_t bytes) -> void* {
    void* p = base + off;
    off += (bytes + 255) & ~(size_t)255;
    return p;
  };
  float* tcr = (float*)alloc(64 * sizeof(float));
  float* tci = (float*)alloc(64 * sizeof(float));
  float* tv = (float*)alloc(128 * sizeof(float));
  float* Mm = (float*)alloc(4096 * sizeof(float));
  float* bias2 = (float*)alloc(64 * sizeof(float));
  float* Sl = (float*)alloc(64 * sizeof(float));
  float2* A2 = (float2*)alloc(262144 * sizeof(float2));
  float* Deff = (float*)alloc(1040384 * sizeof(float));    // [t<128][mm][l]
  float* Dinv = (float*)alloc(520192 * sizeof(float));     // [mm][l][t<64]
  float2* T255 = (float2*)alloc(32385 * sizeof(float2));   // [p][mm]
  float2* T127 = (float2*)alloc(16129 * sizeof(float2));   // [mm][p]
  float2* ftmA = (float2*)alloc(1040384 * sizeof(float2)); // [t<128][mm][c]
  float2* ftmB = (float2*)alloc(1040384 * sizeof(float2));
  float2* flm = (float2*)alloc(520192 * sizeof(float2));   // [mm][l][c]
  if (off > ws_size) return;  // workspace too small -> visible failure
  // aliases with disjoint lifetimes:
  float2* s2 = ftmA;             // after projf consumed ftmA/B
  float2* h2 = ftmB;
  float2* fo_s = (float2*)Deff;  // after projf consumed Deff (4.16 MB)
  float2* fo_h = flm;            // after mix consumed flm

  hipLaunchKernelGGL(ct_setup, dim3(446), dim3(256), 0, stream, Deff, Dinv, T255, T127,
                     temb, strw, strb, stiw, stib, stw, stb, tcr, tci, tv);
  hipLaunchKernelGGL(ct_AM, dim3(129), dim3(64), 0, stream, scw, swr, swi, tcr, tci,
                     c1w, c1b, sweight, tv, Deff, A2, Mm, bias2, Sl);
  hipLaunchKernelGGL(ct_dft, dim3(128, 2, 2), dim3(256), 0, stream, x, T255, ftmA, ftmB);
  hipLaunchKernelGGL(ct_projf, dim3(127, 2), dim3(256), 0, stream, Deff, ftmA, ftmB, flm);
  hipLaunchKernelGGL(ct_mix, dim3(64, 2, 2), dim3(256), 0, stream, flm, A2, Mm,
                     scb, bias2, Sl, s2, h2);
  hipLaunchKernelGGL(ct_proji, dim3(127, 2), dim3(256), 0, stream, Dinv, s2, h2, fo_s, fo_h);
  hipLaunchKernelGGL(ct_idft_final, dim3(64, 2), dim3(256), 0, stream, T127, fo_s, fo_h,
                     c2w, c2b, tv, lns, lnb, out);
}

// Round 7
// 206.907 us; speedup vs baseline: 2.6209x; 1.2161x over previous
//
#include <hip/hip_runtime.h>
#include <math.h>

#define DPI 3.141592653589793238462643383279502884

// ---------------- device helpers ----------------
__device__ __forceinline__ float wave_sum64(float v) {
#pragma unroll
  for (int off = 32; off > 0; off >>= 1) v += __shfl_xor(v, off, 64);
  return v;
}

__device__ __forceinline__ float gelu_tanh(float v) {
  float u = 0.7978845608028654f * (v + 0.044715f * v * v * v);
  return 0.5f * v * (1.0f + tanhf(u));
}

// ---------------- setup: Wigner tables + twiddles + t-emb projections ----------------
__global__ __launch_bounds__(256) void ct_setup(
    float* __restrict__ Deff, float* __restrict__ Dinv,
    float2* __restrict__ T255, float2* __restrict__ T127,
    const float* __restrict__ temb, const float* __restrict__ trw,
    const float* __restrict__ trb, const float* __restrict__ tiw,
    const float* __restrict__ tib, const float* __restrict__ stw,
    const float* __restrict__ stb, float* tcr, float* tci, float* tv) {
  int b = blockIdx.x;
  int tid = threadIdx.x;
  if (b >= 255) {
    if (b == 445) {  // t-emb projections
      if (tid < 64) {
        float ar = trb[tid], ai = tib[tid];
        for (int k = 0; k < 256; ++k) {
          float e = temb[k];
          ar = fmaf(e, trw[k * 64 + tid], ar);
          ai = fmaf(e, tiw[k * 64 + tid], ai);
        }
        tcr[tid] = ar; tci[tid] = ai;
      } else if (tid < 192) {
        int j = tid - 64;
        float a = stb[j];
        for (int k = 0; k < 256; ++k) a = fmaf(temb[k], stw[k * 128 + j], a);
        tv[j] = a;
      }
    } else {  // twiddles
      int id = (b - 255) * 256 + tid;
      if (id < 255 * 127) {
        int p = id / 127, mm = id % 127;
        double ang = 2.0 * DPI * (double)((mm - 63) * p) / 255.0;
        T255[id] = make_float2((float)cos(ang), (float)(-sin(ang)));
      }
      if (id < 127 * 127) {
        int mm = id / 127, p = id % 127;
        double ang = 2.0 * DPI * (double)((mm - 63) * p) / 127.0;
        T127[id] = make_float2((float)cos(ang), (float)sin(ang));
      }
    }
    return;
  }
  // ---- wigner ----
  __shared__ double red[64];
  __shared__ float clf[64];
  int mode = (b < 128) ? 0 : 1;
  if (tid < 64)
    clf[tid] = (float)(-sqrt((2.0 * tid + 1.0) / (4.0 * DPI)));
  int t, mm;
  if (mode == 0) { t = b; mm = tid; }
  else { mm = b - 128; t = tid; }
  double denomN = (mode == 0) ? 255.0 : 127.0;
  double beta = (2.0 * t + 1.0) * DPI / denomN;
  float coeff;
  if (mode == 0) {
    if (tid < 63) {
      int k = 2 * (tid + 1);
      red[tid] = 8.0 * cos((double)k * beta) / (1.0 - (double)k * (double)k);
    } else if (tid == 63) {
      red[63] = 4.0;
    }
    __syncthreads();
    for (int s = 32; s > 0; s >>= 1) {
      if (tid < s) red[tid] += red[tid + s];
      __syncthreads();
    }
    double s = red[0] / 255.0;
    if (t == 127) s *= 0.5;
    coeff = (float)(s * (2.0 * DPI / 255.0));
    if (tid >= 127) return;
  } else {
    __syncthreads();
    coeff = 1.0f;
    if (tid >= 64) return;
  }
  int m = mm - 63;
  double cb = cos(beta);
  double ch = cos(0.5 * beta), sh = sin(0.5 * beta);
  int am = (m < 0) ? -m : m;
  int l0v = (am > 1) ? am : 1;
  double seed;
  if (m >= 1) {
    double j = (double)m;
    double K = exp(0.5 * (lgamma(2.0 * j + 1.0) - lgamma(j) - lgamma(j + 2.0)));
    double sgn = ((m + 1) & 1) ? -1.0 : 1.0;
    seed = sgn * K * pow(ch, j - 1.0) * pow(sh, j + 1.0);
  } else if (m <= -1) {
    double j = (double)(-m);
    double K = exp(0.5 * (lgamma(2.0 * j + 1.0) - lgamma(j) - lgamma(j + 2.0)));
    seed = K * pow(ch, j + 1.0) * pow(sh, j - 1.0);
  } else {
    seed = -sqrt(2.0) * sh * ch;
  }
  float dl = (float)seed, dm1 = 0.0f, S_cur = 0.0f;
  float cbf = (float)cb, mf = (float)m;
  for (int l = 0; l < 64; ++l) {
    float val = 0.0f;
    if (l >= l0v) {
      val = dl * coeff * clf[l];
      float Ld = (float)l, lp = Ld + 1.0f;
      float S_next = sqrtf((lp * lp - mf * mf) * (lp * lp - 1.0f));
      float num1 = (2.0f * Ld + 1.0f) * (Ld * lp * cbf + mf);
      float dn = (num1 * dl - lp * S_cur * dm1) / (Ld * S_next);
      dm1 = dl; dl = dn; S_cur = S_next;
    }
    if (mode == 0) Deff[((size_t)t * 127 + mm) * 64 + l] = val;
    else Dinv[((size_t)mm * 64 + l) * 64 + t] = val;
  }
}

// A2[l][i][o]; M[j][o]; bias2[o]; Sl[l] = sum_t Deff[t][63][l]
__global__ void ct_AM(const float* __restrict__ cw, const float* __restrict__ wr,
                      const float* __restrict__ wi, const float* __restrict__ tcr,
                      const float* __restrict__ tci, const float* __restrict__ c1w,
                      const float* __restrict__ c1b, const float* __restrict__ sw,
                      const float* __restrict__ tv, const float* __restrict__ Deff,
                      float2* __restrict__ A2, float* __restrict__ Mm,
                      float* __restrict__ bias2, float* __restrict__ Sl) {
  int b = blockIdx.x, o = threadIdx.x;
  if (b < 64) {
    int l = b;
    float tr = tcr[l], ti = tci[l];
    for (int i = 0; i < 64; ++i) {
      int idx = (l * 64 + i) * 64 + o;
      float r = wr[idx], s = wi[idx];
      A2[idx] = make_float2(cw[i * 64 + o] + tr * r - ti * s, tr * s + ti * r);
    }
  } else if (b < 128) {
    int j = b - 64;
    float wt = tv[o];
    float acc = 0.f;
    for (int i = 0; i < 64; ++i) acc = fmaf(c1w[j * 64 + i], sw[i * 64 + o], acc);
    Mm[j * 64 + o] = wt * acc;
    if (j == 0) {
      float bb = 0.f;
      for (int i = 0; i < 64; ++i) bb = fmaf(c1b[i], sw[i * 64 + o], bb);
      bias2[o] = wt * bb;
    }
  } else {
    int l = o;
    float s = 0.f;
    for (int t = 0; t < 128; ++t) s += Deff[((size_t)t * 127 + 63) * 64 + l];
    Sl[l] = s;
  }
}

// ---------------- forward DFT: tiled GEMM, planar out, K(p)-split over ph ----------------
// grid (t=128, mh=2, ph=2), block 256.
__global__ __launch_bounds__(256) void ct_dft(const float* __restrict__ x,
                                              const float2* __restrict__ T255,
                                              float* __restrict__ Are, float* __restrict__ Aim,
                                              float* __restrict__ Bre, float* __restrict__ Bim) {
  __shared__ float xs_[64][64];
  __shared__ float tsr[64][64], tsi[64][64];
  int t = blockIdx.x, mh = blockIdx.y, ph = blockIdx.z;
  float* ore = ph ? Bre : Are;
  float* oim = ph ? Bim : Aim;
  int pbase = ph * 128;
  int Ktot = ph ? 127 : 128;
  int tid = threadIdx.x;
  int cg = tid & 15, mg = tid >> 4;
  float accr[4][4], acci[4][4];
#pragma unroll
  for (int j = 0; j < 4; ++j)
#pragma unroll
    for (int q = 0; q < 4; ++q) { accr[j][q] = 0.f; acci[j][q] = 0.f; }
  for (int k0 = 0; k0 < Ktot; k0 += 64) {
    int kn = (Ktot - k0 < 64) ? Ktot - k0 : 64;
    __syncthreads();
    {
      int r = tid >> 2, c4 = (tid & 3) * 16;
      if (r < kn) {
        const float4* src = (const float4*)(x + ((size_t)t * 255 + pbase + k0 + r) * 64 + c4);
        float4* dst = (float4*)&xs_[r][c4];
        dst[0] = src[0]; dst[1] = src[1]; dst[2] = src[2]; dst[3] = src[3];
      }
    }
    for (int e = tid; e < 64 * 64; e += 256) {
      int r = e >> 6, mi = e & 63;
      if (r < kn) {
        int gcol = mh * 64 + mi; if (gcol > 126) gcol = 126;
        float2 tw = T255[(size_t)(pbase + k0 + r) * 127 + gcol];
        tsr[r][mi] = tw.x; tsi[r][mi] = tw.y;
      }
    }
    __syncthreads();
#pragma unroll 4
    for (int k = 0; k < kn; ++k) {
      float4 xv = *(const float4*)&xs_[k][cg * 4];
      float4 tr4 = *(const float4*)&tsr[k][mg * 4];
      float4 ti4 = *(const float4*)&tsi[k][mg * 4];
      float xv4[4] = {xv.x, xv.y, xv.z, xv.w};
      float trv[4] = {tr4.x, tr4.y, tr4.z, tr4.w};
      float tiv[4] = {ti4.x, ti4.y, ti4.z, ti4.w};
#pragma unroll
      for (int j = 0; j < 4; ++j)
#pragma unroll
        for (int q = 0; q < 4; ++q) {
          accr[j][q] = fmaf(xv4[q], trv[j], accr[j][q]);
          acci[j][q] = fmaf(xv4[q], tiv[j], acci[j][q]);
        }
    }
  }
#pragma unroll
  for (int j = 0; j < 4; ++j) {
    int gmm = mh * 64 + mg * 4 + j;
    if (gmm > 126) continue;
    size_t ob = ((size_t)t * 127 + gmm) * 64 + cg * 4;
    *(float4*)(ore + ob) = make_float4(accr[j][0], accr[j][1], accr[j][2], accr[j][3]);
    *(float4*)(oim + ob) = make_float4(acci[j][0], acci[j][1], acci[j][2], acci[j][3]);
  }
}

// ---------------- forward projection, planar, t-split over th ----------------
// grid (mm=127, lh=2, th=2), block 256. flm{A,B}[mm][l][c] partials.
__global__ __launch_bounds__(256) void ct_projf(const float* __restrict__ Deff,
                                                const float* __restrict__ fAre,
                                                const float* __restrict__ fAim,
                                                const float* __restrict__ fBre,
                                                const float* __restrict__ fBim,
                                                float* __restrict__ flmA_re, float* __restrict__ flmA_im,
                                                float* __restrict__ flmB_re, float* __restrict__ flmB_im) {
  __shared__ float Dsh[64][32];
  __shared__ float fr_[64][64], fi_[64][64];
  int mm = blockIdx.x, lh = blockIdx.y, th = blockIdx.z;
  float* ore = th ? flmB_re : flmA_re;
  float* oim = th ? flmB_im : flmA_im;
  int tb = th * 64;
  int tid = threadIdx.x;
  int cg = tid & 15, lg = tid >> 4;
  for (int e = tid; e < 64 * 32; e += 256) {
    int r = e >> 5, li = e & 31;
    Dsh[r][li] = Deff[((size_t)(tb + r) * 127 + mm) * 64 + lh * 32 + li];
  }
  for (int e = tid; e < 64 * 64; e += 256) {
    int r = e >> 6, c = e & 63;
    size_t idx = ((size_t)(tb + r) * 127 + mm) * 64 + c;
    fr_[r][c] = fAre[idx] + fBre[idx];
    fi_[r][c] = fAim[idx] + fBim[idx];
  }
  __syncthreads();
  float ar[2][4], ai[2][4];
#pragma unroll
  for (int li = 0; li < 2; ++li)
#pragma unroll
    for (int q = 0; q < 4; ++q) { ar[li][q] = 0.f; ai[li][q] = 0.f; }
#pragma unroll 4
  for (int k = 0; k < 64; ++k) {
    float4 fr4 = *(const float4*)&fr_[k][cg * 4];
    float4 fi4 = *(const float4*)&fi_[k][cg * 4];
    float2 d2 = *(const float2*)&Dsh[k][lg * 2];
    float frv[4] = {fr4.x, fr4.y, fr4.z, fr4.w};
    float fiv[4] = {fi4.x, fi4.y, fi4.z, fi4.w};
    float dv[2] = {d2.x, d2.y};
#pragma unroll
    for (int li = 0; li < 2; ++li)
#pragma unroll
      for (int q = 0; q < 4; ++q) {
        ar[li][q] = fmaf(dv[li], frv[q], ar[li][q]);
        ai[li][q] = fmaf(dv[li], fiv[q], ai[li][q]);
      }
  }
#pragma unroll
  for (int li = 0; li < 2; ++li) {
    size_t row = ((size_t)mm * 64 + lh * 32 + lg * 2 + li) * 64 + cg * 4;
    *(float4*)(ore + row) = make_float4(ar[li][0], ar[li][1], ar[li][2], ar[li][3]);
    *(float4*)(oim + row) = make_float4(ai[li][0], ai[li][1], ai[li][2], ai[li][3]);
  }
}

// ---------------- fused channel mixes, planar ----------------
// grid (l=64, mh=2, oh=2), block 256. s = flm@A_l + scb ; h = flm@M (+bias spike)
__global__ __launch_bounds__(256) void ct_mix(const float* __restrict__ flmA_re,
                                              const float* __restrict__ flmA_im,
                                              const float* __restrict__ flmB_re,
                                              const float* __restrict__ flmB_im,
                                              const float2* __restrict__ A2,
                                              const float* __restrict__ Mm,
                                              const float* __restrict__ scb,
                                              const float* __restrict__ bias2,
                                              const float* __restrict__ Sl,
                                              float* __restrict__ s_re, float* __restrict__ s_im,
                                              float* __restrict__ h_re, float* __restrict__ h_im) {
  __shared__ float Ar_[64][32], Ai_[64][32], Msh[64][32];
  __shared__ float Br_[64][65], Bi_[64][65];  // [mmIdx][i], pad 65
  int l = blockIdx.x, mh = blockIdx.y, oh = blockIdx.z;
  int tid = threadIdx.x;
  int og = tid & 15, mg = tid >> 4;
  for (int e = tid; e < 64 * 32; e += 256) {
    int r = e >> 5, oi = e & 31;
    float2 a = A2[((size_t)l * 64 + r) * 64 + oh * 32 + oi];
    Ar_[r][oi] = a.x; Ai_[r][oi] = a.y;
    Msh[r][oi] = Mm[r * 64 + oh * 32 + oi];
  }
  for (int e = tid; e < 64 * 64; e += 256) {
    int mi = e >> 6, i = e & 63;
    int gmm = mh * 64 + mi; if (gmm > 126) gmm = 126;
    size_t idx = ((size_t)gmm * 64 + l) * 64 + i;
    Br_[mi][i] = flmA_re[idx] + flmB_re[idx];
    Bi_[mi][i] = flmA_im[idx] + flmB_im[idx];
  }
  __syncthreads();
  int o0 = oh * 32 + og * 2;
  float b0[2] = {scb[o0], scb[o0 + 1]};
  float sr[4][2], si[4][2], hr[4][2], hi[4][2];
#pragma unroll
  for (int jm = 0; jm < 4; ++jm)
#pragma unroll
    for (int qo = 0; qo < 2; ++qo) {
      sr[jm][qo] = b0[qo]; si[jm][qo] = 0.f; hr[jm][qo] = 0.f; hi[jm][qo] = 0.f;
    }
#pragma unroll 4
  for (int k = 0; k < 64; ++k) {
    float2 ar2 = *(const float2*)&Ar_[k][og * 2];
    float2 ai2 = *(const float2*)&Ai_[k][og * 2];
    float2 mv2 = *(const float2*)&Msh[k][og * 2];
    float br4[4], bi4[4];
#pragma unroll
    for (int jm = 0; jm < 4; ++jm) {
      br4[jm] = Br_[mg * 4 + jm][k];
      bi4[jm] = Bi_[mg * 4 + jm][k];
    }
    float arv[2] = {ar2.x, ar2.y}, aiv[2] = {ai2.x, ai2.y}, mvv[2] = {mv2.x, mv2.y};
#pragma unroll
    for (int jm = 0; jm < 4; ++jm)
#pragma unroll
      for (int qo = 0; qo < 2; ++qo) {
        sr[jm][qo] = fmaf(br4[jm], arv[qo], sr[jm][qo]);
        sr[jm][qo] = fmaf(-bi4[jm], aiv[qo], sr[jm][qo]);
        si[jm][qo] = fmaf(br4[jm], aiv[qo], si[jm][qo]);
        si[jm][qo] = fmaf(bi4[jm], arv[qo], si[jm][qo]);
        hr[jm][qo] = fmaf(br4[jm], mvv[qo], hr[jm][qo]);
        hi[jm][qo] = fmaf(bi4[jm], mvv[qo], hi[jm][qo]);
      }
  }
  float Slv = Sl[l];
  float bb[2] = {bias2[o0], bias2[o0 + 1]};
#pragma unroll
  for (int jm = 0; jm < 4; ++jm) {
    int gmm = mh * 64 + mg * 4 + jm;
    if (gmm > 126) continue;
    if (gmm == 63) {
#pragma unroll
      for (int qo = 0; qo < 2; ++qo)
        hr[jm][qo] = fmaf(255.0f * Slv, bb[qo], hr[jm][qo]);
    }
    size_t row = ((size_t)gmm * 64 + l) * 64 + o0;
    *(float2*)(s_re + row) = make_float2(sr[jm][0], sr[jm][1]);
    *(float2*)(s_im + row) = make_float2(si[jm][0], si[jm][1]);
    *(float2*)(h_re + row) = make_float2(hr[jm][0], hr[jm][1]);
    *(float2*)(h_im + row) = make_float2(hi[jm][0], hi[jm][1]);
  }
}

// ---------------- inverse projection, planar, c-split ----------------
// grid (mm=127, br=2, ch=2), block 256. fo[t][mm][c] = sum_l Dinv[mm][l][t]*in[mm][l][c]
__global__ __launch_bounds__(256) void ct_proji(const float* __restrict__ Dinv,
                                                const float* __restrict__ s_re,
                                                const float* __restrict__ s_im,
                                                const float* __restrict__ h_re,
                                                const float* __restrict__ h_im,
                                                float* __restrict__ fos_re, float* __restrict__ fos_im,
                                                float* __restrict__ foh_re, float* __restrict__ foh_im) {
  __shared__ float Dsh[64][64];
  __shared__ float Br_[64][32], Bi_[64][32];
  int mm = blockIdx.x, br = blockIdx.y, ch = blockIdx.z;
  const float* ire = br ? h_re : s_re;
  const float* iim = br ? h_im : s_im;
  float* ore = br ? foh_re : fos_re;
  float* oim = br ? foh_im : fos_im;
  int tid = threadIdx.x;
  int cg = tid & 15, tg = tid >> 4;
  for (int e = tid; e < 64 * 64; e += 256) {
    int r = e >> 6, tt = e & 63;
    Dsh[r][tt] = Dinv[((size_t)mm * 64 + r) * 64 + tt];
  }
  for (int e = tid; e < 64 * 32; e += 256) {
    int r = e >> 5, cc = e & 31;
    size_t idx = ((size_t)mm * 64 + r) * 64 + ch * 32 + cc;
    Br_[r][cc] = ire[idx];
    Bi_[r][cc] = iim[idx];
  }
  __syncthreads();
  float ar[4][2], ai[4][2];
#pragma unroll
  for (int j = 0; j < 4; ++j)
#pragma unroll
    for (int q = 0; q < 2; ++q) { ar[j][q] = 0.f; ai[j][q] = 0.f; }
#pragma unroll 4
  for (int k = 0; k < 64; ++k) {
    float4 d4 = *(const float4*)&Dsh[k][tg * 4];
    float2 fr2 = *(const float2*)&Br_[k][cg * 2];
    float2 fi2 = *(const float2*)&Bi_[k][cg * 2];
    float dv[4] = {d4.x, d4.y, d4.z, d4.w};
    float frv[2] = {fr2.x, fr2.y}, fiv[2] = {fi2.x, fi2.y};
#pragma unroll
    for (int j = 0; j < 4; ++j)
#pragma unroll
      for (int q = 0; q < 2; ++q) {
        ar[j][q] = fmaf(dv[j], frv[q], ar[j][q]);
        ai[j][q] = fmaf(dv[j], fiv[q], ai[j][q]);
      }
  }
#pragma unroll
  for (int j = 0; j < 4; ++j) {
    int t = tg * 4 + j;
    size_t ob = ((size_t)t * 127 + mm) * 64 + ch * 32 + cg * 2;
    *(float2*)(ore + ob) = make_float2(ar[j][0], ar[j][1]);
    *(float2*)(oim + ob) = make_float2(ai[j][0], ai[j][1]);
  }
}

// ---------------- inverse DFT: tiled GEMM, planar, K(mm)-split ----------------
// grid (t=64, br=2, z=4: ph=z>>1, kh=z&1), block 256. Partial sums -> {x,h}sb{A,B}.
__global__ __launch_bounds__(256) void ct_idft(const float2* __restrict__ T127,
                                               const float* __restrict__ fos_re,
                                               const float* __restrict__ fos_im,
                                               const float* __restrict__ foh_re,
                                               const float* __restrict__ foh_im,
                                               float* __restrict__ xsbA, float* __restrict__ xsbB,
                                               float* __restrict__ hsbA, float* __restrict__ hsbB) {
  __shared__ float Ar_[32][64], Ai_[32][64], Br_[32][64], Bi_[32][64];
  int t = blockIdx.x, br = blockIdx.y;
  int z = blockIdx.z;
  int ph = z >> 1, kh = z & 1;
  const float* fre = br ? foh_re : fos_re;
  const float* fim = br ? foh_im : fos_im;
  float* outp = br ? (kh ? hsbB : hsbA) : (kh ? xsbB : xsbA);
  int kbase = kh * 64;
  int Ktot = kh ? 63 : 64;
  int tid = threadIdx.x;
  int cg = tid & 15, pg = tid >> 4;
  float acc[4][4];
#pragma unroll
  for (int j = 0; j < 4; ++j)
#pragma unroll
    for (int q = 0; q < 4; ++q) acc[j][q] = 0.f;
  for (int k0 = 0; k0 < Ktot; k0 += 32) {
    int kn = (Ktot - k0 < 32) ? Ktot - k0 : 32;
    __syncthreads();
    for (int e = tid; e < 32 * 64; e += 256) {
      int r = e >> 6, j = e & 63;
      if (r < kn) {
        int gmm = kbase + k0 + r;
        int gp = ph * 64 + j; if (gp > 126) gp = 126;
        float2 tw = T127[(size_t)gmm * 127 + gp];
        Ar_[r][j] = tw.x; Ai_[r][j] = tw.y;
        size_t bidx = ((size_t)t * 127 + gmm) * 64 + j;
        Br_[r][j] = fre[bidx]; Bi_[r][j] = fim[bidx];
      }
    }
    __syncthreads();
#pragma unroll 4
    for (int k = 0; k < kn; ++k) {
      float4 a_r = *(const float4*)&Ar_[k][pg * 4];
      float4 a_i = *(const float4*)&Ai_[k][pg * 4];
      float4 b_r = *(const float4*)&Br_[k][cg * 4];
      float4 b_i = *(const float4*)&Bi_[k][cg * 4];
      float arv[4] = {a_r.x, a_r.y, a_r.z, a_r.w};
      float aiv[4] = {a_i.x, a_i.y, a_i.z, a_i.w};
      float brv[4] = {b_r.x, b_r.y, b_r.z, b_r.w};
      float biv[4] = {b_i.x, b_i.y, b_i.z, b_i.w};
#pragma unroll
      for (int j = 0; j < 4; ++j)
#pragma unroll
        for (int q = 0; q < 4; ++q) {
          acc[j][q] = fmaf(brv[q], arv[j], acc[j][q]);
          acc[j][q] = fmaf(biv[q], -aiv[j], acc[j][q]);
        }
    }
  }
#pragma unroll
  for (int j = 0; j < 4; ++j) {
    int gp = ph * 64 + pg * 4 + j;
    if (gp > 126) continue;
    *(float4*)(outp + ((size_t)t * 127 + gp) * 64 + cg * 4) =
        make_float4(acc[j][0], acc[j][1], acc[j][2], acc[j][3]);
  }
}

// ---------------- epilogue: one wave per row ----------------
// grid 2032, block 256 (4 waves). row = bid*4 + wave.
__global__ __launch_bounds__(256) void ct_fin(const float* __restrict__ xsbA,
                                              const float* __restrict__ xsbB,
                                              const float* __restrict__ hsbA,
                                              const float* __restrict__ hsbB,
                                              const float* __restrict__ c2w,
                                              const float* __restrict__ c2b,
                                              const float* __restrict__ tv,
                                              const float* __restrict__ lns,
                                              const float* __restrict__ lnb,
                                              float* __restrict__ out) {
  int w = threadIdx.x >> 6, lane = threadIdx.x & 63;
  size_t row = (size_t)blockIdx.x * 4 + w;  // < 8128
  size_t base = row * 64 + lane;
  float hv = hsbA[base] + hsbB[base];
  float xv = xsbA[base] + xsbB[base];
  float acc = c2b[lane] + tv[64 + lane];
#pragma unroll 16
  for (int i = 0; i < 64; ++i)
    acc = fmaf(__shfl(hv, i, 64), c2w[i * 64 + lane], acc);
  float ss = wave_sum64(xv * xv);
  xv = xv / (sqrtf(ss) + 1e-6f);
  float y = xv + acc;
  float g = gelu_tanh(y);
  float mu = wave_sum64(g) * (1.0f / 64.0f);
  float d = g - mu;
  float var = wave_sum64(d * d) * (1.0f / 64.0f);
  out[base] = d * rsqrtf(var + 1e-6f) * lns[lane] + lnb[lane];
}

// ---------------- host launcher ----------------
extern "C" void kernel_launch(void* const* d_in, const int* in_sizes, int n_in,
                              void* d_out, int out_size, void* d_ws, size_t ws_size,
                              hipStream_t stream) {
  const float* x = (const float*)d_in[0];
  const float* temb = (const float*)d_in[1];
  const float* scw = (const float*)d_in[2];
  const float* scb = (const float*)d_in[3];
  const float* swr = (const float*)d_in[4];
  const float* swi = (const float*)d_in[5];
  const float* strw = (const float*)d_in[6];
  const float* strb = (const float*)d_in[7];
  const float* stiw = (const float*)d_in[8];
  const float* stib = (const float*)d_in[9];
  const float* c1w = (const float*)d_in[10];
  const float* c1b = (const float*)d_in[11];
  const float* stw = (const float*)d_in[12];
  const float* stb = (const float*)d_in[13];
  const float* sweight = (const float*)d_in[14];
  const float* c2w = (const float*)d_in[15];
  const float* c2b = (const float*)d_in[16];
  const float* lns = (const float*)d_in[17];
  const float* lnb = (const float*)d_in[18];
  float* out = (float*)d_out;

  char* base = (char*)d_ws;
  size_t off = 0;
  auto alloc = [&](size_t bytes) -> void* {
    void* p = base + off;
    off += (bytes + 255) & ~(size_t)255;
    return p;
  };
  float* tcr = (float*)alloc(64 * sizeof(float));
  float* tci = (float*)alloc(64 * sizeof(float));
  float* tv = (float*)alloc(128 * sizeof(float));
  float* Mm = (float*)alloc(4096 * sizeof(float));
  float* bias2 = (float*)alloc(64 * sizeof(float));
  float* Sl = (float*)alloc(64 * sizeof(float));
  float2* A2 = (float2*)alloc(262144 * sizeof(float2));
  float* Deff = (float*)alloc(1040384 * sizeof(float));   // [t<128][mm][l]
  float* Dinv = (float*)alloc(520192 * sizeof(float));    // [mm][l][t<64]
  float2* T255 = (float2*)alloc(32385 * sizeof(float2));  // [p][mm]
  float2* T127 = (float2*)alloc(16129 * sizeof(float2));  // [mm][p]
  float* ftmA_re = (float*)alloc(1040384 * sizeof(float));
  float* ftmA_im = (float*)alloc(1040384 * sizeof(float));
  float* ftmB_re = (float*)alloc(1040384 * sizeof(float));
  float* ftmB_im = (float*)alloc(1040384 * sizeof(float));
  float* flmA_re = (float*)alloc(520192 * sizeof(float));
  float* flmA_im = (float*)alloc(520192 * sizeof(float));
  float* flmB_re = (float*)alloc(520192 * sizeof(float));
  float* flmB_im = (float*)alloc(520192 * sizeof(float));
  if (off > ws_size) return;  // workspace too small -> visible failure
  // aliases with disjoint lifetimes:
  float* s_re = ftmA_re;          // mix outputs (ftm consumed by projf)
  float* s_im = ftmA_im;
  float* h_re = ftmB_re;
  float* h_im = ftmB_im;
  float* fos_re = Deff;           // proji outputs (Deff consumed by projf/AM)
  float* fos_im = Deff + 520192;
  float* foh_re = flmA_re;        // (flm consumed by mix)
  float* foh_im = flmA_im;
  float* xsbA = flmB_re;          // idft outputs (flmB consumed by mix)
  float* xsbB = flmB_im;
  float* hsbA = ftmA_re;          // (s consumed by proji)
  float* hsbB = ftmA_im;

  hipLaunchKernelGGL(ct_setup, dim3(446), dim3(256), 0, stream, Deff, Dinv, T255, T127,
                     temb, strw, strb, stiw, stib, stw, stb, tcr, tci, tv);
  hipLaunchKernelGGL(ct_AM, dim3(129), dim3(64), 0, stream, scw, swr, swi, tcr, tci,
                     c1w, c1b, sweight, tv, Deff, A2, Mm, bias2, Sl);
  hipLaunchKernelGGL(ct_dft, dim3(128, 2, 2), dim3(256), 0, stream, x, T255,
                     ftmA_re, ftmA_im, ftmB_re, ftmB_im);
  hipLaunchKernelGGL(ct_projf, dim3(127, 2, 2), dim3(256), 0, stream, Deff,
                     ftmA_re, ftmA_im, ftmB_re, ftmB_im,
                     flmA_re, flmA_im, flmB_re, flmB_im);
  hipLaunchKernelGGL(ct_mix, dim3(64, 2, 2), dim3(256), 0, stream,
                     flmA_re, flmA_im, flmB_re, flmB_im, A2, Mm, scb, bias2, Sl,
                     s_re, s_im, h_re, h_im);
  hipLaunchKernelGGL(ct_proji, dim3(127, 2, 2), dim3(256), 0, stream, Dinv,
                     s_re, s_im, h_re, h_im, fos_re, fos_im, foh_re, foh_im);
  hipLaunchKernelGGL(ct_idft, dim3(64, 2, 4), dim3(256), 0, stream, T127,
                     fos_re, fos_im, foh_re, foh_im, xsbA, xsbB, hsbA, hsbB);
  hipLaunchKernelGGL(ct_fin, dim3(2032), dim3(256), 0, stream, xsbA, xsbB, hsbA, hsbB,
                     c2w, c2b, tv, lns, lnb, out);
}